// Round 4
// baseline (1937.451 us; speedup 1.0000x reference)
//
#include <hip/hip_runtime.h>
#include <hip/hip_bf16.h>
#include <math.h>

// Problem constants
#define NN 40000
#define EE 640000
#define BB 8192
#define IN_DIM 768
#define META_DIM 6
#define XDIM 774      // IN+META
#define HID 256
#define OUT_D 128
#define NEXP 4
#define NET_T 3
#define REL_D 200
#define NLAY 4
#define FF_D 512

typedef __attribute__((ext_vector_type(8))) short short8;
typedef __attribute__((ext_vector_type(4))) float f32x4;

__device__ __forceinline__ ushort f2bf(float f) {
    union { float f; unsigned u; } a; a.f = f;
    unsigned u = a.u;
    unsigned r = (u + 0x7FFFu + ((u >> 16) & 1u)) >> 16;  // RNE
    return (ushort)r;
}
__device__ __forceinline__ float bf2f(ushort h) {
    union { unsigned u; float f; } a; a.u = ((unsigned)h) << 16;
    return a.f;
}

// ---------------------------------------------------------------------------
// fp32 -> (hi,lo) bf16 split with K padding.
// ---------------------------------------------------------------------------
__global__ void cvt_kernel(const float* __restrict__ src, int ldsrc, int Kreal,
                           ushort* __restrict__ hi, ushort* __restrict__ lo,
                           int R, int ldp)
{
    size_t i = (size_t)blockIdx.x * blockDim.x + threadIdx.x;
    size_t total = (size_t)R * ldp;
    if (i >= total) return;
    int col = (int)(i % ldp);
    int row = (int)(i / ldp);
    float v = (col < Kreal) ? src[(size_t)row * ldsrc + col] : 0.f;
    ushort h = f2bf(v);
    float rem = v - bf2f(h);
    hi[i] = h;
    lo[i] = f2bf(rem);
}

static void cvt(const float* src, int ldsrc, int Kreal, ushort* hi, ushort* lo,
                int R, int ldp, hipStream_t s)
{
    size_t total = (size_t)R * ldp;
    cvt_kernel<<<(int)((total + 255) / 256), 256, 0, s>>>(src, ldsrc, Kreal, hi, lo, R, ldp);
}

// ---------------------------------------------------------------------------
// Full-N (256-wide) split-bf16 3xMFMA GEMM.
//   C[M,256] = act(A[M,K] @ B[256,K]^T + bias + res)
// BM=64, BN=256, 4 waves of 64x64. A fetched from HBM exactly once.
// OUT_SPLIT: write (hi,lo) bf16 pair instead of fp32.
// K%32==0 (padded buffers). M arbitrary (clamped staging, guarded stores).
// ---------------------------------------------------------------------------
template<int ACT, int HAS_RES, int OUT_SPLIT>
__global__ __launch_bounds__(256) void mfma3_n256(
    const ushort* __restrict__ Ahi, const ushort* __restrict__ Alo, int lda,
    const ushort* __restrict__ Bhi, const ushort* __restrict__ Blo, int ldb,
    const float* __restrict__ bias, const float* __restrict__ res,
    float* __restrict__ C, ushort* __restrict__ Chi, ushort* __restrict__ Clo,
    int M, int K)
{
    __shared__ __align__(16) ushort Ash[64 * 40];
    __shared__ __align__(16) ushort Asl[64 * 40];
    __shared__ __align__(16) ushort Bsh[256 * 40];
    __shared__ __align__(16) ushort Bsl[256 * 40];

    int bm = blockIdx.x * 64;
    int t = threadIdx.x;
    int wv = t >> 6, lane = t & 63;
    int quad = lane >> 4, r = lane & 15;

    f32x4 acc[4][4];
#pragma unroll
    for (int i = 0; i < 4; i++)
#pragma unroll
        for (int j = 0; j < 4; j++) acc[i][j] = (f32x4){0.f, 0.f, 0.f, 0.f};

    for (int k0 = 0; k0 < K; k0 += 32) {
        {   // A tile 64x32: 256 chunks, 1 per thread (hi + lo)
            int row = t >> 2, c8 = t & 3;
            int grow = bm + row; if (grow > M - 1) grow = M - 1;
            size_t off = (size_t)grow * lda + k0 + c8 * 8;
            *(short8*)&Ash[row * 40 + c8 * 8] = *(const short8*)(Ahi + off);
            *(short8*)&Asl[row * 40 + c8 * 8] = *(const short8*)(Alo + off);
        }
#pragma unroll
        for (int i = 0; i < 4; i++) {   // B tile 256x32: 1024 chunks
            int idx = t + i * 256;
            int row = idx >> 2, c8 = idx & 3;
            size_t off = (size_t)row * ldb + k0 + c8 * 8;
            *(short8*)&Bsh[row * 40 + c8 * 8] = *(const short8*)(Bhi + off);
            *(short8*)&Bsl[row * 40 + c8 * 8] = *(const short8*)(Blo + off);
        }
        __syncthreads();

        short8 ah[4], al[4];
#pragma unroll
        for (int i = 0; i < 4; i++) {
            int ro = (i * 16 + r) * 40 + quad * 8;
            ah[i] = *(const short8*)&Ash[ro];
            al[i] = *(const short8*)&Asl[ro];
        }
#pragma unroll
        for (int j = 0; j < 4; j++) {
            int ro = (wv * 64 + j * 16 + r) * 40 + quad * 8;
            short8 bh = *(const short8*)&Bsh[ro];
            short8 bl = *(const short8*)&Bsl[ro];
#pragma unroll
            for (int i = 0; i < 4; i++)
                acc[i][j] = __builtin_amdgcn_mfma_f32_16x16x32_bf16(ah[i], bh, acc[i][j], 0, 0, 0);
#pragma unroll
            for (int i = 0; i < 4; i++)
                acc[i][j] = __builtin_amdgcn_mfma_f32_16x16x32_bf16(ah[i], bl, acc[i][j], 0, 0, 0);
#pragma unroll
            for (int i = 0; i < 4; i++)
                acc[i][j] = __builtin_amdgcn_mfma_f32_16x16x32_bf16(al[i], bh, acc[i][j], 0, 0, 0);
        }
        __syncthreads();
    }

    // epilogue
#pragma unroll
    for (int j = 0; j < 4; j++) {
        int col = wv * 64 + j * 16 + r;
        float bc = bias ? bias[col] : 0.f;
#pragma unroll
        for (int i = 0; i < 4; i++) {
#pragma unroll
            for (int reg = 0; reg < 4; reg++) {
                int row = bm + i * 16 + quad * 4 + reg;
                if (row >= M) continue;
                float v = acc[i][j][reg] + bc;
                if (HAS_RES) v += res[(size_t)row * 256 + col];
                if (ACT == 1) v = fmaxf(v, 0.f);
                else if (ACT == 2) v = (v > 0.f) ? v : expm1f(v);
                if (OUT_SPLIT) {
                    ushort h = f2bf(v);
                    Chi[(size_t)row * 256 + col] = h;
                    Clo[(size_t)row * 256 + col] = f2bf(v - bf2f(h));
                } else {
                    C[(size_t)row * 256 + col] = v;
                }
            }
        }
    }
}

template<int ACT, int HAS_RES, int OUT_SPLIT>
static void n256_launch(const ushort* Ahi, const ushort* Alo, int lda,
                        const ushort* Bhi, const ushort* Blo, int ldb,
                        const float* bias, const float* res,
                        float* C, ushort* Chi, ushort* Clo,
                        int M, int K, hipStream_t s)
{
    mfma3_n256<ACT, HAS_RES, OUT_SPLIT><<<(M + 63) / 64, 256, 0, s>>>(
        Ahi, Alo, lda, Bhi, Blo, ldb, bias, res, C, Chi, Clo, M, K);
}

// ---------------------------------------------------------------------------
// Split-bf16 3xMFMA GEMM, 128x64 tile (for N=128 outputs).
// ---------------------------------------------------------------------------
template<int ACT, int HAS_RES>
__global__ __launch_bounds__(256) void mfma_gemm3(
    const ushort* __restrict__ Ahi, const ushort* __restrict__ Alo, int lda,
    const ushort* __restrict__ Bhi, const ushort* __restrict__ Blo, int ldb,
    const float* __restrict__ bias, const float* __restrict__ res,
    float* __restrict__ C, int M, int Nn, int K)
{
    __shared__ __align__(16) ushort Ash[128 * 40];
    __shared__ __align__(16) ushort Asl[128 * 40];
    __shared__ __align__(16) ushort Bsh[64 * 40];
    __shared__ __align__(16) ushort Bsl[64 * 40];

    int bn = blockIdx.x * 64;
    int bm = blockIdx.y * 128;
    int t = threadIdx.x;
    int wave = t >> 6, lane = t & 63;
    int wm = wave & 1, wn = wave >> 1;
    int quad = lane >> 4, r = lane & 15;

    f32x4 acc[4][2];
#pragma unroll
    for (int i = 0; i < 4; i++)
#pragma unroll
        for (int j = 0; j < 2; j++) acc[i][j] = (f32x4){0.f, 0.f, 0.f, 0.f};

    for (int k0 = 0; k0 < K; k0 += 32) {
#pragma unroll
        for (int i = 0; i < 2; i++) {
            int idx = t + i * 256;
            int row = idx >> 2, c8 = idx & 3;
            int grow = bm + row; if (grow > M - 1) grow = M - 1;
            size_t off = (size_t)grow * lda + k0 + c8 * 8;
            *(short8*)&Ash[row * 40 + c8 * 8] = *(const short8*)(Ahi + off);
            *(short8*)&Asl[row * 40 + c8 * 8] = *(const short8*)(Alo + off);
        }
        {
            int row = t >> 2, c8 = t & 3;
            size_t off = (size_t)(bn + row) * ldb + k0 + c8 * 8;
            *(short8*)&Bsh[row * 40 + c8 * 8] = *(const short8*)(Bhi + off);
            *(short8*)&Bsl[row * 40 + c8 * 8] = *(const short8*)(Blo + off);
        }
        __syncthreads();

        short8 ah[4], al[4], bh[2], bl[2];
#pragma unroll
        for (int i = 0; i < 4; i++) {
            int ro = (wm * 64 + i * 16 + r) * 40 + quad * 8;
            ah[i] = *(const short8*)&Ash[ro];
            al[i] = *(const short8*)&Asl[ro];
        }
#pragma unroll
        for (int j = 0; j < 2; j++) {
            int ro = (wn * 32 + j * 16 + r) * 40 + quad * 8;
            bh[j] = *(const short8*)&Bsh[ro];
            bl[j] = *(const short8*)&Bsl[ro];
        }
#pragma unroll
        for (int i = 0; i < 4; i++)
#pragma unroll
            for (int j = 0; j < 2; j++)
                acc[i][j] = __builtin_amdgcn_mfma_f32_16x16x32_bf16(ah[i], bh[j], acc[i][j], 0, 0, 0);
#pragma unroll
        for (int i = 0; i < 4; i++)
#pragma unroll
            for (int j = 0; j < 2; j++)
                acc[i][j] = __builtin_amdgcn_mfma_f32_16x16x32_bf16(ah[i], bl[j], acc[i][j], 0, 0, 0);
#pragma unroll
        for (int i = 0; i < 4; i++)
#pragma unroll
            for (int j = 0; j < 2; j++)
                acc[i][j] = __builtin_amdgcn_mfma_f32_16x16x32_bf16(al[i], bh[j], acc[i][j], 0, 0, 0);
        __syncthreads();
    }

    float bcol[2];
#pragma unroll
    for (int j = 0; j < 2; j++)
        bcol[j] = bias ? bias[bn + wn * 32 + j * 16 + r] : 0.f;
#pragma unroll
    for (int i = 0; i < 4; i++) {
#pragma unroll
        for (int j = 0; j < 2; j++) {
            int col = bn + wn * 32 + j * 16 + r;
#pragma unroll
            for (int reg = 0; reg < 4; reg++) {
                int row = bm + wm * 64 + i * 16 + quad * 4 + reg;
                if (row >= M) continue;
                float v = acc[i][j][reg] + bcol[j];
                if (HAS_RES) v += res[(size_t)row * Nn + col];
                if (ACT == 1) v = fmaxf(v, 0.f);
                else if (ACT == 2) v = (v > 0.f) ? v : expm1f(v);
                C[(size_t)row * Nn + col] = v;
            }
        }
    }
}

template<int ACT, int HAS_RES>
static void mfma3_launch(const ushort* Ahi, const ushort* Alo, int lda,
                         const ushort* Bhi, const ushort* Blo, int ldb,
                         const float* bias, const float* res, float* C,
                         int M, int Nn, int K, hipStream_t s)
{
    dim3 grid(Nn / 64, (M + 127) / 128);
    mfma_gemm3<ACT, HAS_RES><<<grid, 256, 0, s>>>(Ahi, Alo, lda, Bhi, Blo, ldb,
                                                  bias, res, C, M, Nn, K);
}

// ---------------------------------------------------------------------------
// fp32 tiled GEMM (tiny me_w1 only)
// ---------------------------------------------------------------------------
template<int ACT>
__global__ void gemm_kernel(const float* __restrict__ A, int lda,
                            const float* __restrict__ Bw,
                            const float* __restrict__ bias,
                            const float* __restrict__ res,
                            float* __restrict__ C, int M, int Nn, int K)
{
    __shared__ float As[16][68];
    __shared__ float Bs[16][68];
    int bm = blockIdx.y * 64, bn = blockIdx.x * 64;
    int t = threadIdx.x;
    int tx = t & 15, ty = t >> 4;
    float acc[4][4] = {{0.f}};

    for (int k0 = 0; k0 < K; k0 += 16) {
#pragma unroll
        for (int i = 0; i < 4; i++) {
            int l = t * 4 + i; int mm = l >> 4, kk = l & 15;
            int gm = bm + mm, gk = k0 + kk;
            As[kk][mm] = (gm < M && gk < K) ? A[(size_t)gm * lda + gk] : 0.f;
        }
#pragma unroll
        for (int i = 0; i < 4; i++) {
            int l = t * 4 + i; int nn = l >> 4, kk = l & 15;
            int gn = bn + nn, gk = k0 + kk;
            Bs[kk][nn] = (gn < Nn && gk < K) ? Bw[(size_t)gn * K + gk] : 0.f;
        }
        __syncthreads();
#pragma unroll
        for (int kk = 0; kk < 16; kk++) {
            float4 a4 = *reinterpret_cast<const float4*>(&As[kk][ty * 4]);
            float4 b4 = *reinterpret_cast<const float4*>(&Bs[kk][tx * 4]);
            float a0[4] = {a4.x, a4.y, a4.z, a4.w};
            float b0[4] = {b4.x, b4.y, b4.z, b4.w};
#pragma unroll
            for (int i = 0; i < 4; i++)
#pragma unroll
                for (int j = 0; j < 4; j++)
                    acc[i][j] += a0[i] * b0[j];
        }
        __syncthreads();
    }
#pragma unroll
    for (int i = 0; i < 4; i++) {
        int gm = bm + ty * 4 + i; if (gm >= M) continue;
#pragma unroll
        for (int j = 0; j < 4; j++) {
            int gn = bn + tx * 4 + j; if (gn >= Nn) continue;
            float v = acc[i][j];
            if (bias) v += bias[gn];
            if (res)  v += res[(size_t)gm * Nn + gn];
            if (ACT == 1) v = fmaxf(v, 0.f);
            else if (ACT == 2) v = (v > 0.f) ? v : expm1f(v);
            C[(size_t)gm * Nn + gn] = v;
        }
    }
}

static void launch_gemm(int act, const float* A, int lda, const float* Bw,
                        const float* bias, const float* res, float* C,
                        int M, int Nn, int K, hipStream_t s)
{
    dim3 grid((Nn + 63) / 64, (M + 63) / 64);
    dim3 blk(256);
    if (act == 0)      gemm_kernel<0><<<grid, blk, 0, s>>>(A, lda, Bw, bias, res, C, M, Nn, K);
    else if (act == 1) gemm_kernel<1><<<grid, blk, 0, s>>>(A, lda, Bw, bias, res, C, M, Nn, K);
    else               gemm_kernel<2><<<grid, blk, 0, s>>>(A, lda, Bw, bias, res, C, M, Nn, K);
}

// ---------------------------------------------------------------------------
// bf16 MFMA GEMM (downstream-of-gate path): C = act(A@B^T + bias), batched.
// ---------------------------------------------------------------------------
template<int ACT, int A_BF16, int OUT_BF16>
__global__ __launch_bounds__(256) void mfma_gemm(
    const void* __restrict__ Ap, size_t strideAz,
    const float* __restrict__ Bw, size_t strideBz,
    const float* __restrict__ bias, size_t strideBiasz,
    void* __restrict__ Cp, size_t strideCz,
    int M, int Nn, int K)
{
    __shared__ __align__(16) ushort As[128 * 40];
    __shared__ __align__(16) ushort Bs[64 * 40];

    int z = blockIdx.z;
    const float*  Af  = (const float*)Ap  + (A_BF16 ? 0 : z * strideAz);
    const ushort* Ab  = (const ushort*)Ap + (A_BF16 ? z * strideAz : 0);
    const float*  Bwz = Bw + z * strideBz;
    const float*  bz  = bias ? bias + z * strideBiasz : nullptr;
    float*  Cf = (float*)Cp  + (OUT_BF16 ? 0 : z * strideCz);
    ushort* Cb = (ushort*)Cp + (OUT_BF16 ? z * strideCz : 0);

    int bn = blockIdx.x * 64;
    int bm = blockIdx.y * 128;
    int t = threadIdx.x;
    int wave = t >> 6, lane = t & 63;
    int wm = wave & 1, wn = wave >> 1;
    int quad = lane >> 4, r = lane & 15;

    f32x4 acc[4][2];
#pragma unroll
    for (int i = 0; i < 4; i++)
#pragma unroll
        for (int j = 0; j < 2; j++) acc[i][j] = (f32x4){0.f, 0.f, 0.f, 0.f};

    for (int k0 = 0; k0 < K; k0 += 32) {
        if (A_BF16) {
#pragma unroll
            for (int i = 0; i < 2; i++) {
                int idx = t + i * 256;
                int row = idx >> 2, c8 = idx & 3;
                short8 v = *(const short8*)(Ab + (size_t)(bm + row) * K + k0 + c8 * 8);
                *(short8*)&As[row * 40 + c8 * 8] = v;
            }
        } else {
#pragma unroll
            for (int i = 0; i < 4; i++) {
                int idx = t + i * 256;
                int row = idx >> 3, c4 = idx & 7;
                float4 f = *(const float4*)(Af + (size_t)(bm + row) * K + k0 + c4 * 4);
                ushort4 u; u.x = f2bf(f.x); u.y = f2bf(f.y); u.z = f2bf(f.z); u.w = f2bf(f.w);
                *(ushort4*)&As[row * 40 + c4 * 4] = u;
            }
        }
#pragma unroll
        for (int i = 0; i < 2; i++) {
            int idx = t + i * 256;
            int row = idx >> 3, c4 = idx & 7;
            float4 f = *(const float4*)(Bwz + (size_t)(bn + row) * K + k0 + c4 * 4);
            ushort4 u; u.x = f2bf(f.x); u.y = f2bf(f.y); u.z = f2bf(f.z); u.w = f2bf(f.w);
            *(ushort4*)&Bs[row * 40 + c4 * 4] = u;
        }
        __syncthreads();

        short8 af[4], bf[2];
#pragma unroll
        for (int i = 0; i < 4; i++)
            af[i] = *(const short8*)&As[(wm * 64 + i * 16 + r) * 40 + quad * 8];
#pragma unroll
        for (int j = 0; j < 2; j++)
            bf[j] = *(const short8*)&Bs[(wn * 32 + j * 16 + r) * 40 + quad * 8];
#pragma unroll
        for (int i = 0; i < 4; i++)
#pragma unroll
            for (int j = 0; j < 2; j++)
                acc[i][j] = __builtin_amdgcn_mfma_f32_16x16x32_bf16(af[i], bf[j], acc[i][j], 0, 0, 0);
        __syncthreads();
    }

    float bcol[2];
#pragma unroll
    for (int j = 0; j < 2; j++)
        bcol[j] = bz ? bz[bn + wn * 32 + j * 16 + r] : 0.f;
#pragma unroll
    for (int i = 0; i < 4; i++) {
#pragma unroll
        for (int j = 0; j < 2; j++) {
            int col = bn + wn * 32 + j * 16 + r;
#pragma unroll
            for (int reg = 0; reg < 4; reg++) {
                int row = bm + wm * 64 + i * 16 + quad * 4 + reg;
                float v = acc[i][j][reg] + bcol[j];
                if (ACT == 1) v = fmaxf(v, 0.f);
                if (OUT_BF16) Cb[(size_t)row * Nn + col] = f2bf(v);
                else          Cf[(size_t)row * Nn + col] = v;
            }
        }
    }
}

template<int ACT, int A_BF16, int OUT_BF16>
static void mfma_launch(const void* A, size_t sAz, const float* Bw, size_t sBz,
                        const float* bias, size_t sbz, void* C, size_t sCz,
                        int M, int Nn, int K, int batch, hipStream_t s)
{
    dim3 grid(Nn / 64, M / 128, batch);
    mfma_gemm<ACT, A_BF16, OUT_BF16><<<grid, 256, 0, s>>>(A, sAz, Bw, sBz, bias, sbz, C, sCz, M, Nn, K);
}

// ---------------------------------------------------------------------------
// GNN helper kernels
// ---------------------------------------------------------------------------
__global__ void sisj_kernel(const float* __restrict__ Wx, const float* __restrict__ a,
                            float* __restrict__ s_i, float* __restrict__ s_j, int n)
{
    int t = threadIdx.x; int w = t >> 6, l = t & 63;
    int m = blockIdx.x * 4 + w; if (m >= n) return;
    const float* r = Wx + (size_t)m * HID;
    float v1 = 0.f, v2 = 0.f;
#pragma unroll
    for (int i = 0; i < 4; i++) {
        float xv = r[l + 64 * i];
        v1 += xv * a[l + 64 * i];
        v2 += xv * a[HID + l + 64 * i];
    }
    for (int off = 32; off; off >>= 1) { v1 += __shfl_down(v1, off); v2 += __shfl_down(v2, off); }
    if (l == 0) { s_i[m] = v1; s_j[m] = v2; }
}

__global__ void rs_kernel(const float* __restrict__ Wr, const float* __restrict__ rel,
                          const float* __restrict__ a3, float* __restrict__ rs)
{
    __shared__ float red[256];
    int tt = blockIdx.x; int j = threadIdx.x;
    const float* relr = rel + tt * REL_D;
    const float* wr = Wr + (size_t)j * REL_D;
    float wsum = 0.f;
    for (int k = 0; k < REL_D; k++) wsum += wr[k] * relr[k];
    red[j] = wsum * a3[j];
    __syncthreads();
    for (int s2 = 128; s2; s2 >>= 1) { if (j < s2) red[j] += red[j + s2]; __syncthreads(); }
    if (j == 0) rs[tt] = red[0];
}

// ---- CSR build ----
__global__ void deg_kernel(const int* __restrict__ dst, int* __restrict__ deg)
{
    int e = blockIdx.x * blockDim.x + threadIdx.x;
    if (e < EE) atomicAdd(&deg[dst[e]], 1);
}

__global__ void scan_kernel(const int* __restrict__ deg, int* __restrict__ rowstart,
                            int* __restrict__ cursor, int n)
{
    __shared__ int buf[1024];
    __shared__ int carry;
    int t = threadIdx.x;
    if (t == 0) carry = 0;
    __syncthreads();
    for (int c = 0; c < n; c += 1024) {
        int v = (c + t < n) ? deg[c + t] : 0;
        buf[t] = v;
        __syncthreads();
        for (int off = 1; off < 1024; off <<= 1) {
            int x = (t >= off) ? buf[t - off] : 0;
            __syncthreads();
            buf[t] += x;
            __syncthreads();
        }
        int incl = buf[t];
        int base = carry;
        if (c + t < n) { rowstart[c + t] = base + incl - v; cursor[c + t] = base + incl - v; }
        __syncthreads();
        if (t == 1023) carry = base + incl;
        __syncthreads();
    }
    if (t == 0) rowstart[n] = carry;
}

__global__ void fill_kernel(const int* __restrict__ src, const int* __restrict__ dst,
                            const int* __restrict__ et, int* __restrict__ cursor,
                            unsigned* __restrict__ csr_val)
{
    int e = blockIdx.x * blockDim.x + threadIdx.x;
    if (e >= EE) return;
    int d = dst[e];
    int pos = atomicAdd(&cursor[d], 1);
    csr_val[pos] = (unsigned)src[e] | ((unsigned)et[e] << 16);
}

// ---- fused attention-softmax aggregation: wave per dst node ----
__global__ void csr_agg_kernel(const unsigned* __restrict__ csr_val,
                               const int* __restrict__ rowstart,
                               const float* __restrict__ s_i, const float* __restrict__ s_j,
                               const float* __restrict__ rsv,
                               const float* __restrict__ Wx, float* __restrict__ agg)
{
    int t = threadIdx.x; int w = t >> 6, l = t & 63;
    int node = blockIdx.x * 4 + w; if (node >= NN) return;
    int start = rowstart[node], end = rowstart[node + 1];
    float r0 = rsv[0], r1 = rsv[1], r2 = rsv[2];
    float si = s_i[node];

    float m = -INFINITY;
    for (int i = start + l; i < end; i += 64) {
        unsigned v = csr_val[i];
        int s = v & 0xFFFF; int et = v >> 16;
        float rr = (et == 0) ? r0 : ((et == 1) ? r1 : r2);
        float lg = si + s_j[s] + rr;
        lg = (lg >= 0.f) ? lg : 0.2f * lg;
        m = fmaxf(m, lg);
    }
    for (int off = 32; off; off >>= 1) m = fmaxf(m, __shfl_down(m, off));
    m = __shfl(m, 0);

    float a0 = 0.f, a1 = 0.f, a2 = 0.f, a3 = 0.f, ssum = 0.f;
    for (int c = start; c < end; c += 64) {
        int nchunk = min(64, end - c);
        float wgt = 0.f; int sidx = 0;
        if (l < nchunk) {
            unsigned v = csr_val[c + l];
            sidx = v & 0xFFFF; int et = v >> 16;
            float rr = (et == 0) ? r0 : ((et == 1) ? r1 : r2);
            float lg = si + s_j[sidx] + rr;
            lg = (lg >= 0.f) ? lg : 0.2f * lg;
            wgt = expf(lg - m);
            ssum += wgt;
        }
        for (int j = 0; j < nchunk; j++) {
            float wj = __shfl(wgt, j);
            int sj = __shfl(sidx, j);
            const float* wr = Wx + (size_t)sj * HID;
            a0 += wj * wr[l];
            a1 += wj * wr[l + 64];
            a2 += wj * wr[l + 128];
            a3 += wj * wr[l + 192];
        }
    }
    for (int off = 32; off; off >>= 1) ssum += __shfl_down(ssum, off);
    ssum = __shfl(ssum, 0);
    float inv = 1.f / (ssum + 1e-16f);
    float* ar = agg + (size_t)node * HID;
    ar[l] = a0 * inv; ar[l + 64] = a1 * inv; ar[l + 128] = a2 * inv; ar[l + 192] = a3 * inv;
}

// row-L2-normalize a split (hi,lo) pair in place
__global__ void rownorm_split(ushort* __restrict__ hi, ushort* __restrict__ lo, int n)
{
    int t = threadIdx.x; int w = t >> 6, l = t & 63;
    int m = blockIdx.x * 4 + w; if (m >= n) return;
    size_t base = (size_t)m * HID;
    float vals[4]; float q = 0.f;
#pragma unroll
    for (int i = 0; i < 4; i++) {
        vals[i] = bf2f(hi[base + l + 64 * i]) + bf2f(lo[base + l + 64 * i]);
        q += vals[i] * vals[i];
    }
    for (int off = 32; off; off >>= 1) q += __shfl_down(q, off);
    q = __shfl(q, 0);
    float inv = 1.f / fmaxf(sqrtf(q), 1e-12f);
#pragma unroll
    for (int i = 0; i < 4; i++) {
        float nv = vals[i] * inv;
        ushort h = f2bf(nv);
        hi[base + l + 64 * i] = h;
        lo[base + l + 64 * i] = f2bf(nv - bf2f(h));
    }
}

// ---------------------------------------------------------------------------
// MoE gating (fp32)
// ---------------------------------------------------------------------------
__global__ void moe_gate_kernel(const float* __restrict__ xv, const float* __restrict__ gate_w,
                                const float* __restrict__ noise_w, const float* __restrict__ eps,
                                float* __restrict__ comb, float* __restrict__ tmpsum)
{
    __shared__ float part[4];
    int t = threadIdx.x; int w = t >> 6, l = t & 63;
    if (t < 4) part[t] = 0.f;
    __syncthreads();
    int b = blockIdx.x * 4 + w;
    const float* xr = xv + (size_t)b * OUT_D;
    float x0 = xr[l], x1 = xr[l + 64];
    float dots[5];
#pragma unroll
    for (int e = 0; e < 4; e++) {
        const float* gw = gate_w + e * OUT_D;
        float v = x0 * gw[l] + x1 * gw[l + 64];
        for (int off = 32; off; off >>= 1) v += __shfl_down(v, off);
        dots[e] = v;
    }
    {
        float v = x0 * noise_w[l] + x1 * noise_w[l + 64];
        for (int off = 32; off; off >>= 1) v += __shfl_down(v, off);
        dots[4] = v;
    }
    if (l == 0) {
        float xg = dots[4];
        float nsd = (xg > 20.f) ? xg : log1pf(expf(xg));
        float hv[4];
#pragma unroll
        for (int e = 0; e < 4; e++) hv[e] = dots[e] + eps[(size_t)b * 4 + e] * nsd;
        int i1 = 0;
        for (int e = 1; e < 4; e++) if (hv[e] < hv[i1]) i1 = e;
        int i2 = -1;
        for (int e = 0; e < 4; e++) { if (e == i1) continue; if (i2 < 0 || hv[e] < hv[i2]) i2 = e; }
        int k1 = -1, k2 = -1;
        for (int e = 0; e < 4; e++) { if (e != i1 && e != i2) { if (k1 < 0) k1 = e; else k2 = e; } }
        float mm = fmaxf(hv[k1], hv[k2]);
        float e1 = expf(hv[k1] - mm), e2 = expf(hv[k2] - mm);
        float s = e1 + e2;
        float L[4] = {0.f, 0.f, 0.f, 0.f};
        L[k1] = e1 / s; L[k2] = e2 / s;
#pragma unroll
        for (int e = 0; e < 4; e++) comb[(size_t)b * 4 + e] = L[e];
        atomicAdd(&part[k1], L[k1]);
        atomicAdd(&part[k2], L[k2]);
    }
    __syncthreads();
    if (t < 4) atomicAdd(&tmpsum[t], part[t]);
}

__global__ void moe_combine_kernel(const float* __restrict__ eo, const float* __restrict__ comb,
                                   float* __restrict__ zout)
{
    int idx = blockIdx.x * blockDim.x + threadIdx.x;
    if (idx >= BB * OUT_D) return;
    int b = idx >> 7, o = idx & 127;
    const size_t S = (size_t)BB * OUT_D;
    float v = comb[b * 4 + 0] * eo[idx] + comb[b * 4 + 1] * eo[idx + S]
            + comb[b * 4 + 2] * eo[idx + 2 * S] + comb[b * 4 + 3] * eo[idx + 3 * S];
    zout[(size_t)b * (3 * OUT_D) + o] = v;
}

__global__ void loss_kernel(const float* __restrict__ tmpsum, float* __restrict__ out)
{
    if (threadIdx.x == 0 && blockIdx.x == 0) {
        float total = 0.f;
        for (int v = 0; v < 3; v++) {
            const float* tp = tmpsum + v * 4;
            float mean = (tp[0] + tp[1] + tp[2] + tp[3]) * 0.25f;
            float var = 0.f;
            for (int e = 0; e < 4; e++) { float d = tp[e] - mean; var += d * d; }
            var /= 3.f;
            float r = sqrtf(var) / mean;
            total += r * r;
        }
        out[0] = total;
    }
}

// ---------------------------------------------------------------------------
// Transformer small kernels
// ---------------------------------------------------------------------------
__global__ void attn_kernel(const float* __restrict__ qkv, float* __restrict__ o)
{
    int t = threadIdx.x;
    int half = t >> 5;
    int d = t & 31;
    int task = blockIdx.x * 8 + half;   // b*4 + h
    int b = task >> 2, h = task & 3;
    const float* base = qkv + (size_t)b * 3 * 384 + h * 32;
    float q0 = base[d],       q1 = base[384 + d],       q2 = base[768 + d];
    float k0 = base[128 + d], k1 = base[384 + 128 + d], k2 = base[768 + 128 + d];
    float v0 = base[256 + d], v1 = base[384 + 256 + d], v2 = base[768 + 256 + d];
    float s[3][3];
    s[0][0] = q0 * k0; s[0][1] = q0 * k1; s[0][2] = q0 * k2;
    s[1][0] = q1 * k0; s[1][1] = q1 * k1; s[1][2] = q1 * k2;
    s[2][0] = q2 * k0; s[2][1] = q2 * k1; s[2][2] = q2 * k2;
#pragma unroll
    for (int i = 0; i < 3; i++)
#pragma unroll
        for (int j = 0; j < 3; j++) {
            float v = s[i][j];
            for (int off = 16; off; off >>= 1) v += __shfl_xor(v, off, 32);
            s[i][j] = v;
        }
    const float scale = 0.17677669529663687f;
    float outv[3];
#pragma unroll
    for (int i = 0; i < 3; i++) {
        float a0 = s[i][0] * scale, a1 = s[i][1] * scale, a2 = s[i][2] * scale;
        float m = fmaxf(a0, fmaxf(a1, a2));
        float e0 = expf(a0 - m), e1 = expf(a1 - m), e2 = expf(a2 - m);
        float inv = 1.f / (e0 + e1 + e2);
        outv[i] = (e0 * v0 + e1 * v1 + e2 * v2) * inv;
    }
    float* ob = o + (size_t)b * 3 * 128 + h * 32;
    ob[d] = outv[0]; ob[128 + d] = outv[1]; ob[256 + d] = outv[2];
}

__global__ void ln_residual_kernel(float* __restrict__ x, const float* __restrict__ add,
                                   const float* __restrict__ g, const float* __restrict__ bta, int M)
{
    int t = threadIdx.x; int w = t >> 6, l = t & 63;
    int row = blockIdx.x * 4 + w; if (row >= M) return;
    float* xr = x + (size_t)row * 128;
    const float* ar = add + (size_t)row * 128;
    float v0 = xr[l] + ar[l], v1 = xr[l + 64] + ar[l + 64];
    float s = v0 + v1;
    for (int off = 32; off; off >>= 1) s += __shfl_down(s, off);
    s = __shfl(s, 0);
    float mu = s * (1.f / 128.f);
    float d0 = v0 - mu, d1 = v1 - mu;
    float q = d0 * d0 + d1 * d1;
    for (int off = 32; off; off >>= 1) q += __shfl_down(q, off);
    q = __shfl(q, 0);
    float inv = rsqrtf(q * (1.f / 128.f) + 1e-5f);
    xr[l]      = d0 * inv * g[l] + bta[l];
    xr[l + 64] = d1 * inv * g[l + 64] + bta[l + 64];
}

__global__ void clf_kernel(const float* __restrict__ z, const float* __restrict__ w,
                           const float* __restrict__ b, float* __restrict__ out)
{
    int t = threadIdx.x; int wv = t >> 6, l = t & 63;
    int row = blockIdx.x * 4 + wv; if (row >= BB) return;
    const float* zr = z + (size_t)row * 384;
    float v0 = 0.f, v1 = 0.f;
    for (int i = l; i < 384; i += 64) {
        float zz = zr[i];
        v0 += zz * w[i];
        v1 += zz * w[384 + i];
    }
    for (int off = 32; off; off >>= 1) { v0 += __shfl_down(v0, off); v1 += __shfl_down(v1, off); }
    if (l == 0) { out[row * 2] = v0 + b[0]; out[row * 2 + 1] = v1 + b[1]; }
}

// ---------------------------------------------------------------------------
// Orchestration
// ---------------------------------------------------------------------------
extern "C" void kernel_launch(void* const* d_in, const int* in_sizes, int n_in,
                              void* d_out, int out_size, void* d_ws, size_t ws_size,
                              hipStream_t stream)
{
    const float* x         = (const float*)d_in[0];
    const float* noise     = (const float*)d_in[1];
    const float* g_lin1_w  = (const float*)d_in[2];
    const float* g_lin1_b  = (const float*)d_in[3];
    const float* conv_W    = (const float*)d_in[4];
    const float* conv_Wr   = (const float*)d_in[5];
    const float* conv_a    = (const float*)d_in[6];
    const float* conv_Wres = (const float*)d_in[7];
    const float* conv_rel  = (const float*)d_in[8];
    const float* g_lin2_w  = (const float*)d_in[9];
    const float* g_lin2_b  = (const float*)d_in[10];
    const float* te_w      = (const float*)d_in[11];
    const float* te_b      = (const float*)d_in[12];
    const float* me_w1     = (const float*)d_in[13];
    const float* me_b1     = (const float*)d_in[14];
    const float* me_w2     = (const float*)d_in[15];
    const float* me_b2     = (const float*)d_in[16];
    const float* moe_gate_w  = (const float*)d_in[17];
    const float* moe_noise_w = (const float*)d_in[18];
    const float* moe_w1    = (const float*)d_in[19];
    const float* moe_b1    = (const float*)d_in[20];
    const float* moe_w2    = (const float*)d_in[21];
    const float* moe_b2    = (const float*)d_in[22];
    const float* tf_qkv_w  = (const float*)d_in[23];
    const float* tf_qkv_b  = (const float*)d_in[24];
    const float* tf_out_w  = (const float*)d_in[25];
    const float* tf_out_b  = (const float*)d_in[26];
    const float* tf_ln1_g  = (const float*)d_in[27];
    const float* tf_ln1_b  = (const float*)d_in[28];
    const float* tf_ff1_w  = (const float*)d_in[29];
    const float* tf_ff1_b  = (const float*)d_in[30];
    const float* tf_ff2_w  = (const float*)d_in[31];
    const float* tf_ff2_b  = (const float*)d_in[32];
    const float* tf_ln2_g  = (const float*)d_in[33];
    const float* tf_ln2_b  = (const float*)d_in[34];
    const float* clf_w     = (const float*)d_in[35];
    const float* clf_b     = (const float*)d_in[36];
    const int*   edge_index = (const int*)d_in[37];
    const int*   edge_type  = (const int*)d_in[38];

    float* ws = (float*)d_ws;

    // Arena (float offsets)
    //  A @ 0          : pairA (hi,lo 40000x256 bf16) / later qkv
    //  B @ 10,240,000 : wx / graph / ff1(bf16)
    //  C @ 22,822,912 : agg / later x_mh, h1bf, attn_o, tmp1
    //  D @ 33,062,912 : pairB / later z, x_t, x_m, eo
    //  M @ 43,302,912 : misc + CSR
    //  X @ 44,200,000 : xhi/xlo, weight pair, me-hidden pair
    const size_t F_A = 0;
    const size_t F_B = 10240000;
    const size_t F_C = 22822912;
    const size_t F_D = 33062912;
    const size_t F_M = 43302912;
    const size_t F_X = 44200000;

    ushort* hAhi  = (ushort*)(ws + F_A);
    ushort* hAlo  = (ushort*)(ws + F_A + 5120000);
    float* qkv    = ws + F_A;
    float* wx     = ws + F_B;
    float* graph  = ws + F_B;
    ushort* ff1bf = (ushort*)(ws + F_B);
    float* agg    = ws + F_C;
    float* x_mh   = ws + F_C;
    ushort* h1bf  = (ushort*)(ws + F_C);
    float* attn_o = ws + F_C;
    float* tmp1   = ws + F_C + 3200000;
    ushort* hBhi  = (ushort*)(ws + F_D);
    ushort* hBlo  = (ushort*)(ws + F_D + 5120000);
    float* z      = ws + F_D;
    float* x_t    = ws + F_D + 3200000;
    float* x_m    = ws + F_D + 4300000;
    float* eo     = ws + F_D + 5400000;

    float* s_i    = ws + F_M;
    float* s_j    = ws + F_M + 40000;
    float* rsv    = ws + F_M + 80000;
    float* comb   = ws + F_M + 80016;
    float* tmpsum = ws + F_M + 112784;
    int* deg      = (int*)(ws + F_M + 120000);
    int* rowstart = (int*)(ws + F_M + 161000);
    int* cursor   = (int*)(ws + F_M + 202000);
    unsigned* csr_val = (unsigned*)(ws + F_M + 242000);

    ushort* xhi  = (ushort*)(ws + F_X);                 // 40000x800
    ushort* xlo  = (ushort*)(ws + F_X + 16000000);
    ushort* wbh  = (ushort*)(ws + F_X + 32000000);      // up to 256x800
    ushort* wbl  = (ushort*)(ws + F_X + 32110000);
    ushort* mhhi = (ushort*)(ws + F_X + 32220000);      // 8192x256
    ushort* mhlo = (ushort*)(ws + F_X + 33280000);

    const int* srcv = edge_index;
    const int* dstv = edge_index + EE;

    // ---- 0. CSR build ----
    hipMemsetAsync(deg, 0, NN * sizeof(int), stream);
    deg_kernel<<<(EE + 255) / 256, 256, 0, stream>>>(dstv, deg);
    scan_kernel<<<1, 1024, 0, stream>>>(deg, rowstart, cursor, NN);
    fill_kernel<<<(EE + 255) / 256, 256, 0, stream>>>(srcv, dstv, edge_type, cursor, csr_val);

    // ---- 1. h = relu(x @ g_lin1_w.T + b) -> split pair A ----
    cvt(x, XDIM, XDIM, xhi, xlo, NN, 800, stream);
    cvt(g_lin1_w, XDIM, XDIM, wbh, wbl, HID, 800, stream);
    n256_launch<1, 0, 1>(xhi, xlo, 800, wbh, wbl, 800, g_lin1_b, nullptr,
                         nullptr, hAhi, hAlo, NN, 800, stream);

    // ---- 2. two HGN layers (pair ping-pong A->B->A) ----
    ushort *inhi = hAhi, *inlo = hAlo, *outhi = hBhi, *outlo = hBlo;
    for (int layer = 0; layer < 2; layer++) {
        const float* W    = conv_W    + (size_t)layer * HID * HID;
        const float* Wr   = conv_Wr   + (size_t)layer * HID * REL_D;
        const float* a    = conv_a    + (size_t)layer * 3 * HID;
        const float* Wres = conv_Wres + (size_t)layer * HID * HID;
        const float* rel  = conv_rel  + (size_t)layer * NET_T * REL_D;

        cvt(W, HID, HID, wbh, wbl, HID, HID, stream);
        n256_launch<0, 0, 0>(inhi, inlo, HID, wbh, wbl, HID, nullptr, nullptr,
                             wx, nullptr, nullptr, NN, HID, stream);
        sisj_kernel<<<NN / 4, 256, 0, stream>>>(wx, a, s_i, s_j, NN);
        rs_kernel<<<NET_T, 256, 0, stream>>>(Wr, rel, a + 2 * HID, rsv);
        csr_agg_kernel<<<NN / 4, 256, 0, stream>>>(csr_val, rowstart, s_i, s_j, rsv, wx, agg);
        cvt(Wres, HID, HID, wbh, wbl, HID, HID, stream);
        n256_launch<2, 1, 1>(inhi, inlo, HID, wbh, wbl, HID, nullptr, agg,
                             nullptr, outhi, outlo, NN, HID, stream);
        ushort* th = inhi; inhi = outhi; outhi = th;
        ushort* tl = inlo; inlo = outlo; outlo = tl;
    }
    // final layer output is pair A again (inhi/inlo == hAhi/hAlo)
    rownorm_split<<<NN / 4, 256, 0, stream>>>(inhi, inlo, NN);

    // ---- 3. graph = relu(h2 @ g_lin2.T + b) ----
    cvt(g_lin2_w, HID, HID, wbh, wbl, OUT_D, HID, stream);
    mfma3_launch<1, 0>(inhi, inlo, HID, wbh, wbl, HID, g_lin2_b, nullptr, graph,
                       NN, OUT_D, HID, stream);

    // ---- 4. view encoders ----
    cvt(te_w, IN_DIM, IN_DIM, wbh, wbl, OUT_D, IN_DIM, stream);
    mfma3_launch<1, 0>(xhi, xlo, 800, wbh, wbl, IN_DIM, te_b, nullptr, x_t,
                       BB, OUT_D, IN_DIM, stream);
    launch_gemm(1, x + IN_DIM, XDIM, me_w1, me_b1, nullptr, x_mh, BB, HID, META_DIM, stream);
    cvt(x_mh, HID, HID, mhhi, mhlo, BB, HID, stream);
    cvt(me_w2, HID, HID, wbh, wbl, OUT_D, HID, stream);
    mfma3_launch<1, 0>(mhhi, mhlo, HID, wbh, wbl, HID, me_b2, nullptr, x_m,
                       BB, OUT_D, HID, stream);

    // ---- 5. MoE per view: fp32 gate, bf16 MFMA experts ----
    hipMemsetAsync(tmpsum, 0, 16 * sizeof(float), stream);
    const float* xvs[3] = { graph, x_t, x_m };
    for (int v = 0; v < 3; v++) {
        const float* xv = xvs[v];
        moe_gate_kernel<<<BB / 4, 256, 0, stream>>>(
            xv, moe_gate_w + (size_t)v * NEXP * OUT_D, moe_noise_w + (size_t)v * OUT_D,
            noise + (size_t)v * BB * NEXP, comb, tmpsum + v * 4);
        mfma_launch<1, 0, 1>(xv, 0,
                             moe_w1 + (size_t)v * 4 * FF_D * OUT_D, (size_t)FF_D * OUT_D,
                             moe_b1 + (size_t)v * 4 * FF_D, FF_D,
                             h1bf, (size_t)BB * FF_D,
                             BB, FF_D, OUT_D, 4, stream);
        mfma_launch<0, 1, 0>(h1bf, (size_t)BB * FF_D,
                             moe_w2 + (size_t)v * 4 * OUT_D * FF_D, (size_t)OUT_D * FF_D,
                             moe_b2 + (size_t)v * 4 * OUT_D, OUT_D,
                             eo, (size_t)BB * OUT_D,
                             BB, OUT_D, FF_D, 4, stream);
        moe_combine_kernel<<<(BB * OUT_D) / 256, 256, 0, stream>>>(eo, comb, z + v * OUT_D);
    }

    // ---- 6. transformer x4 on z (24576,128) ----
    const int MT = BB * 3;
    for (int li = 0; li < NLAY; li++) {
        mfma_launch<0, 0, 0>(z, 0, tf_qkv_w + (size_t)li * 384 * 128, 0,
                             tf_qkv_b + li * 384, 0, qkv, 0, MT, 384, 128, 1, stream);
        attn_kernel<<<(BB * 4) / 8, 256, 0, stream>>>(qkv, attn_o);
        mfma_launch<0, 0, 0>(attn_o, 0, tf_out_w + (size_t)li * 128 * 128, 0,
                             tf_out_b + li * 128, 0, tmp1, 0, MT, 128, 128, 1, stream);
        ln_residual_kernel<<<MT / 4, 256, 0, stream>>>(z, tmp1, tf_ln1_g + li * 128, tf_ln1_b + li * 128, MT);
        mfma_launch<1, 0, 1>(z, 0, tf_ff1_w + (size_t)li * 512 * 128, 0,
                             tf_ff1_b + li * 512, 0, ff1bf, 0, MT, 512, 128, 1, stream);
        mfma_launch<0, 1, 0>(ff1bf, 0, tf_ff2_w + (size_t)li * 128 * 512, 0,
                             tf_ff2_b + li * 128, 0, tmp1, 0, MT, 128, 512, 1, stream);
        ln_residual_kernel<<<MT / 4, 256, 0, stream>>>(z, tmp1, tf_ln2_g + li * 128, tf_ln2_b + li * 128, MT);
    }

    // ---- 7. classifier + loss ----
    clf_kernel<<<BB / 4, 256, 0, stream>>>(z, clf_w, clf_b, (float*)d_out);
    loss_kernel<<<1, 64, 0, stream>>>(tmpsum, (float*)d_out + BB * 2);
}

// Round 5
// 1877.187 us; speedup vs baseline: 1.0321x; 1.0321x over previous
//
#include <hip/hip_runtime.h>
#include <hip/hip_bf16.h>
#include <math.h>

// Problem constants
#define NN 40000
#define EE 640000
#define BB 8192
#define IN_DIM 768
#define META_DIM 6
#define XDIM 774      // IN+META
#define HID 256
#define OUT_D 128
#define NEXP 4
#define NET_T 3
#define REL_D 200
#define NLAY 4
#define FF_D 512

typedef __attribute__((ext_vector_type(8))) short short8;
typedef __attribute__((ext_vector_type(4))) float f32x4;

__device__ __forceinline__ ushort f2bf(float f) {
    union { float f; unsigned u; } a; a.f = f;
    unsigned u = a.u;
    unsigned r = (u + 0x7FFFu + ((u >> 16) & 1u)) >> 16;  // RNE
    return (ushort)r;
}
__device__ __forceinline__ float bf2f(ushort h) {
    union { unsigned u; float f; } a; a.u = ((unsigned)h) << 16;
    return a.f;
}

// ---------------------------------------------------------------------------
// fp32 -> (hi,lo) bf16 split with K padding.
// ---------------------------------------------------------------------------
__global__ void cvt_kernel(const float* __restrict__ src, int ldsrc, int Kreal,
                           ushort* __restrict__ hi, ushort* __restrict__ lo,
                           int R, int ldp)
{
    size_t i = (size_t)blockIdx.x * blockDim.x + threadIdx.x;
    size_t total = (size_t)R * ldp;
    if (i >= total) return;
    int col = (int)(i % ldp);
    int row = (int)(i / ldp);
    float v = (col < Kreal) ? src[(size_t)row * ldsrc + col] : 0.f;
    ushort h = f2bf(v);
    float rem = v - bf2f(h);
    hi[i] = h;
    lo[i] = f2bf(rem);
}

static void cvt(const float* src, int ldsrc, int Kreal, ushort* hi, ushort* lo,
                int R, int ldp, hipStream_t s)
{
    size_t total = (size_t)R * ldp;
    cvt_kernel<<<(int)((total + 255) / 256), 256, 0, s>>>(src, ldsrc, Kreal, hi, lo, R, ldp);
}

// ---------------------------------------------------------------------------
// Split-bf16 (3xMFMA) fp32-precision GEMM, 128x128 block tile.
//   C[M,N] = act(A[M,K] @ B[N,K]^T + bias + res)
// 4 waves, each a 64x64 wave-tile (16 f32x4 acc). K-step 32.
// Per wave per K-step: 16 ds_read_b128 -> 48 MFMA (3 MFMA/read).
// N%128==0, K%32==0 (padded buffers). M arbitrary.
// ACT: 0=none,1=relu,2=elu. HAS_RES: +res. OUT_SPLIT: write (hi,lo) pair.
// ---------------------------------------------------------------------------
template<int ACT, int HAS_RES, int OUT_SPLIT>
__global__ __launch_bounds__(256) void mfma3_128(
    const ushort* __restrict__ Ahi, const ushort* __restrict__ Alo, int lda,
    const ushort* __restrict__ Bhi, const ushort* __restrict__ Blo, int ldb,
    const float* __restrict__ bias, const float* __restrict__ res,
    float* __restrict__ C, ushort* __restrict__ Chi, ushort* __restrict__ Clo,
    int M, int Nn, int K)
{
    __shared__ __align__(16) ushort Ash[128 * 40];
    __shared__ __align__(16) ushort Asl[128 * 40];
    __shared__ __align__(16) ushort Bsh[128 * 40];
    __shared__ __align__(16) ushort Bsl[128 * 40];

    int bn = blockIdx.x * 128;
    int bm = blockIdx.y * 128;
    int t = threadIdx.x;
    int wave = t >> 6, lane = t & 63;
    int wm = wave & 1, wn = wave >> 1;
    int quad = lane >> 4, r = lane & 15;

    f32x4 acc[4][4];
#pragma unroll
    for (int i = 0; i < 4; i++)
#pragma unroll
        for (int j = 0; j < 4; j++) acc[i][j] = (f32x4){0.f, 0.f, 0.f, 0.f};

    for (int k0 = 0; k0 < K; k0 += 32) {
        // stage A tile 128x32 (pair): 512 chunks each of hi/lo
#pragma unroll
        for (int i = 0; i < 2; i++) {
            int idx = t + i * 256;
            int row = idx >> 2, c8 = idx & 3;
            int grow = bm + row; if (grow > M - 1) grow = M - 1;
            size_t off = (size_t)grow * lda + k0 + c8 * 8;
            *(short8*)&Ash[row * 40 + c8 * 8] = *(const short8*)(Ahi + off);
            *(short8*)&Asl[row * 40 + c8 * 8] = *(const short8*)(Alo + off);
        }
        // stage B tile 128x32 (pair)
#pragma unroll
        for (int i = 0; i < 2; i++) {
            int idx = t + i * 256;
            int row = idx >> 2, c8 = idx & 3;
            size_t off = (size_t)(bn + row) * ldb + k0 + c8 * 8;
            *(short8*)&Bsh[row * 40 + c8 * 8] = *(const short8*)(Bhi + off);
            *(short8*)&Bsl[row * 40 + c8 * 8] = *(const short8*)(Blo + off);
        }
        __syncthreads();

        short8 ah[4], al[4], bh[4], bl[4];
#pragma unroll
        for (int i = 0; i < 4; i++) {
            int ro = (wm * 64 + i * 16 + r) * 40 + quad * 8;
            ah[i] = *(const short8*)&Ash[ro];
            al[i] = *(const short8*)&Asl[ro];
        }
#pragma unroll
        for (int j = 0; j < 4; j++) {
            int ro = (wn * 64 + j * 16 + r) * 40 + quad * 8;
            bh[j] = *(const short8*)&Bsh[ro];
            bl[j] = *(const short8*)&Bsl[ro];
        }
#pragma unroll
        for (int j = 0; j < 4; j++)
#pragma unroll
            for (int i = 0; i < 4; i++)
                acc[i][j] = __builtin_amdgcn_mfma_f32_16x16x32_bf16(ah[i], bh[j], acc[i][j], 0, 0, 0);
#pragma unroll
        for (int j = 0; j < 4; j++)
#pragma unroll
            for (int i = 0; i < 4; i++)
                acc[i][j] = __builtin_amdgcn_mfma_f32_16x16x32_bf16(ah[i], bl[j], acc[i][j], 0, 0, 0);
#pragma unroll
        for (int j = 0; j < 4; j++)
#pragma unroll
            for (int i = 0; i < 4; i++)
                acc[i][j] = __builtin_amdgcn_mfma_f32_16x16x32_bf16(al[i], bh[j], acc[i][j], 0, 0, 0);
        __syncthreads();
    }

    // epilogue
#pragma unroll
    for (int j = 0; j < 4; j++) {
        int col = bn + wn * 64 + j * 16 + r;
        float bc = bias ? bias[col] : 0.f;
#pragma unroll
        for (int i = 0; i < 4; i++) {
#pragma unroll
            for (int reg = 0; reg < 4; reg++) {
                int row = bm + wm * 64 + i * 16 + quad * 4 + reg;
                if (row >= M) continue;
                float v = acc[i][j][reg] + bc;
                if (HAS_RES) v += res[(size_t)row * Nn + col];
                if (ACT == 1) v = fmaxf(v, 0.f);
                else if (ACT == 2) v = (v > 0.f) ? v : expm1f(v);
                if (OUT_SPLIT) {
                    ushort h = f2bf(v);
                    Chi[(size_t)row * Nn + col] = h;
                    Clo[(size_t)row * Nn + col] = f2bf(v - bf2f(h));
                } else {
                    C[(size_t)row * Nn + col] = v;
                }
            }
        }
    }
}

template<int ACT, int HAS_RES, int OUT_SPLIT>
static void m128_launch(const ushort* Ahi, const ushort* Alo, int lda,
                        const ushort* Bhi, const ushort* Blo, int ldb,
                        const float* bias, const float* res,
                        float* C, ushort* Chi, ushort* Clo,
                        int M, int Nn, int K, hipStream_t s)
{
    dim3 grid(Nn / 128, (M + 127) / 128);
    mfma3_128<ACT, HAS_RES, OUT_SPLIT><<<grid, 256, 0, s>>>(
        Ahi, Alo, lda, Bhi, Blo, ldb, bias, res, C, Chi, Clo, M, Nn, K);
}

// ---------------------------------------------------------------------------
// fp32 tiled GEMM (tiny me_w1 only, K=6)
// ---------------------------------------------------------------------------
template<int ACT>
__global__ void gemm_kernel(const float* __restrict__ A, int lda,
                            const float* __restrict__ Bw,
                            const float* __restrict__ bias,
                            const float* __restrict__ res,
                            float* __restrict__ C, int M, int Nn, int K)
{
    __shared__ float As[16][68];
    __shared__ float Bs[16][68];
    int bm = blockIdx.y * 64, bn = blockIdx.x * 64;
    int t = threadIdx.x;
    int tx = t & 15, ty = t >> 4;
    float acc[4][4] = {{0.f}};

    for (int k0 = 0; k0 < K; k0 += 16) {
#pragma unroll
        for (int i = 0; i < 4; i++) {
            int l = t * 4 + i; int mm = l >> 4, kk = l & 15;
            int gm = bm + mm, gk = k0 + kk;
            As[kk][mm] = (gm < M && gk < K) ? A[(size_t)gm * lda + gk] : 0.f;
        }
#pragma unroll
        for (int i = 0; i < 4; i++) {
            int l = t * 4 + i; int nn = l >> 4, kk = l & 15;
            int gn = bn + nn, gk = k0 + kk;
            Bs[kk][nn] = (gn < Nn && gk < K) ? Bw[(size_t)gn * K + gk] : 0.f;
        }
        __syncthreads();
#pragma unroll
        for (int kk = 0; kk < 16; kk++) {
            float4 a4 = *reinterpret_cast<const float4*>(&As[kk][ty * 4]);
            float4 b4 = *reinterpret_cast<const float4*>(&Bs[kk][tx * 4]);
            float a0[4] = {a4.x, a4.y, a4.z, a4.w};
            float b0[4] = {b4.x, b4.y, b4.z, b4.w};
#pragma unroll
            for (int i = 0; i < 4; i++)
#pragma unroll
                for (int j = 0; j < 4; j++)
                    acc[i][j] += a0[i] * b0[j];
        }
        __syncthreads();
    }
#pragma unroll
    for (int i = 0; i < 4; i++) {
        int gm = bm + ty * 4 + i; if (gm >= M) continue;
#pragma unroll
        for (int j = 0; j < 4; j++) {
            int gn = bn + tx * 4 + j; if (gn >= Nn) continue;
            float v = acc[i][j];
            if (bias) v += bias[gn];
            if (res)  v += res[(size_t)gm * Nn + gn];
            if (ACT == 1) v = fmaxf(v, 0.f);
            else if (ACT == 2) v = (v > 0.f) ? v : expm1f(v);
            C[(size_t)gm * Nn + gn] = v;
        }
    }
}

static void launch_gemm(int act, const float* A, int lda, const float* Bw,
                        const float* bias, const float* res, float* C,
                        int M, int Nn, int K, hipStream_t s)
{
    dim3 grid((Nn + 63) / 64, (M + 63) / 64);
    dim3 blk(256);
    if (act == 0)      gemm_kernel<0><<<grid, blk, 0, s>>>(A, lda, Bw, bias, res, C, M, Nn, K);
    else if (act == 1) gemm_kernel<1><<<grid, blk, 0, s>>>(A, lda, Bw, bias, res, C, M, Nn, K);
    else               gemm_kernel<2><<<grid, blk, 0, s>>>(A, lda, Bw, bias, res, C, M, Nn, K);
}

// ---------------------------------------------------------------------------
// bf16 MFMA GEMM (downstream-of-gate path): C = act(A@B^T + bias), batched.
// ---------------------------------------------------------------------------
template<int ACT, int A_BF16, int OUT_BF16>
__global__ __launch_bounds__(256) void mfma_gemm(
    const void* __restrict__ Ap, size_t strideAz,
    const float* __restrict__ Bw, size_t strideBz,
    const float* __restrict__ bias, size_t strideBiasz,
    void* __restrict__ Cp, size_t strideCz,
    int M, int Nn, int K)
{
    __shared__ __align__(16) ushort As[128 * 40];
    __shared__ __align__(16) ushort Bs[64 * 40];

    int z = blockIdx.z;
    const float*  Af  = (const float*)Ap  + (A_BF16 ? 0 : z * strideAz);
    const ushort* Ab  = (const ushort*)Ap + (A_BF16 ? z * strideAz : 0);
    const float*  Bwz = Bw + z * strideBz;
    const float*  bz  = bias ? bias + z * strideBiasz : nullptr;
    float*  Cf = (float*)Cp  + (OUT_BF16 ? 0 : z * strideCz);
    ushort* Cb = (ushort*)Cp + (OUT_BF16 ? z * strideCz : 0);

    int bn = blockIdx.x * 64;
    int bm = blockIdx.y * 128;
    int t = threadIdx.x;
    int wave = t >> 6, lane = t & 63;
    int wm = wave & 1, wn = wave >> 1;
    int quad = lane >> 4, r = lane & 15;

    f32x4 acc[4][2];
#pragma unroll
    for (int i = 0; i < 4; i++)
#pragma unroll
        for (int j = 0; j < 2; j++) acc[i][j] = (f32x4){0.f, 0.f, 0.f, 0.f};

    for (int k0 = 0; k0 < K; k0 += 32) {
        if (A_BF16) {
#pragma unroll
            for (int i = 0; i < 2; i++) {
                int idx = t + i * 256;
                int row = idx >> 2, c8 = idx & 3;
                short8 v = *(const short8*)(Ab + (size_t)(bm + row) * K + k0 + c8 * 8);
                *(short8*)&As[row * 40 + c8 * 8] = v;
            }
        } else {
#pragma unroll
            for (int i = 0; i < 4; i++) {
                int idx = t + i * 256;
                int row = idx >> 3, c4 = idx & 7;
                float4 f = *(const float4*)(Af + (size_t)(bm + row) * K + k0 + c4 * 4);
                ushort4 u; u.x = f2bf(f.x); u.y = f2bf(f.y); u.z = f2bf(f.z); u.w = f2bf(f.w);
                *(ushort4*)&As[row * 40 + c4 * 4] = u;
            }
        }
#pragma unroll
        for (int i = 0; i < 2; i++) {
            int idx = t + i * 256;
            int row = idx >> 3, c4 = idx & 7;
            float4 f = *(const float4*)(Bwz + (size_t)(bn + row) * K + k0 + c4 * 4);
            ushort4 u; u.x = f2bf(f.x); u.y = f2bf(f.y); u.z = f2bf(f.z); u.w = f2bf(f.w);
            *(ushort4*)&Bs[row * 40 + c4 * 4] = u;
        }
        __syncthreads();

        short8 af[4], bf[2];
#pragma unroll
        for (int i = 0; i < 4; i++)
            af[i] = *(const short8*)&As[(wm * 64 + i * 16 + r) * 40 + quad * 8];
#pragma unroll
        for (int j = 0; j < 2; j++)
            bf[j] = *(const short8*)&Bs[(wn * 32 + j * 16 + r) * 40 + quad * 8];
#pragma unroll
        for (int i = 0; i < 4; i++)
#pragma unroll
            for (int j = 0; j < 2; j++)
                acc[i][j] = __builtin_amdgcn_mfma_f32_16x16x32_bf16(af[i], bf[j], acc[i][j], 0, 0, 0);
        __syncthreads();
    }

    float bcol[2];
#pragma unroll
    for (int j = 0; j < 2; j++)
        bcol[j] = bz ? bz[bn + wn * 32 + j * 16 + r] : 0.f;
#pragma unroll
    for (int i = 0; i < 4; i++) {
#pragma unroll
        for (int j = 0; j < 2; j++) {
            int col = bn + wn * 32 + j * 16 + r;
#pragma unroll
            for (int reg = 0; reg < 4; reg++) {
                int row = bm + wm * 64 + i * 16 + quad * 4 + reg;
                float v = acc[i][j][reg] + bcol[j];
                if (ACT == 1) v = fmaxf(v, 0.f);
                if (OUT_BF16) Cb[(size_t)row * Nn + col] = f2bf(v);
                else          Cf[(size_t)row * Nn + col] = v;
            }
        }
    }
}

template<int ACT, int A_BF16, int OUT_BF16>
static void mfma_launch(const void* A, size_t sAz, const float* Bw, size_t sBz,
                        const float* bias, size_t sbz, void* C, size_t sCz,
                        int M, int Nn, int K, int batch, hipStream_t s)
{
    dim3 grid(Nn / 64, M / 128, batch);
    mfma_gemm<ACT, A_BF16, OUT_BF16><<<grid, 256, 0, s>>>(A, sAz, Bw, sBz, bias, sbz, C, sCz, M, Nn, K);
}

// ---------------------------------------------------------------------------
// GNN helper kernels
// ---------------------------------------------------------------------------
__global__ void sisj_kernel(const float* __restrict__ Wx, const float* __restrict__ a,
                            float* __restrict__ s_i, float* __restrict__ s_j, int n)
{
    int t = threadIdx.x; int w = t >> 6, l = t & 63;
    int m = blockIdx.x * 4 + w; if (m >= n) return;
    const float* r = Wx + (size_t)m * HID;
    float v1 = 0.f, v2 = 0.f;
#pragma unroll
    for (int i = 0; i < 4; i++) {
        float xv = r[l + 64 * i];
        v1 += xv * a[l + 64 * i];
        v2 += xv * a[HID + l + 64 * i];
    }
    for (int off = 32; off; off >>= 1) { v1 += __shfl_down(v1, off); v2 += __shfl_down(v2, off); }
    if (l == 0) { s_i[m] = v1; s_j[m] = v2; }
}

__global__ void rs_kernel(const float* __restrict__ Wr, const float* __restrict__ rel,
                          const float* __restrict__ a3, float* __restrict__ rs)
{
    __shared__ float red[256];
    int tt = blockIdx.x; int j = threadIdx.x;
    const float* relr = rel + tt * REL_D;
    const float* wr = Wr + (size_t)j * REL_D;
    float wsum = 0.f;
    for (int k = 0; k < REL_D; k++) wsum += wr[k] * relr[k];
    red[j] = wsum * a3[j];
    __syncthreads();
    for (int s2 = 128; s2; s2 >>= 1) { if (j < s2) red[j] += red[j + s2]; __syncthreads(); }
    if (j == 0) rs[tt] = red[0];
}

// ---- CSR build ----
__global__ void deg_kernel(const int* __restrict__ dst, int* __restrict__ deg)
{
    int e = blockIdx.x * blockDim.x + threadIdx.x;
    if (e < EE) atomicAdd(&deg[dst[e]], 1);
}

__global__ void scan_kernel(const int* __restrict__ deg, int* __restrict__ rowstart,
                            int* __restrict__ cursor, int n)
{
    __shared__ int buf[1024];
    __shared__ int carry;
    int t = threadIdx.x;
    if (t == 0) carry = 0;
    __syncthreads();
    for (int c = 0; c < n; c += 1024) {
        int v = (c + t < n) ? deg[c + t] : 0;
        buf[t] = v;
        __syncthreads();
        for (int off = 1; off < 1024; off <<= 1) {
            int x = (t >= off) ? buf[t - off] : 0;
            __syncthreads();
            buf[t] += x;
            __syncthreads();
        }
        int incl = buf[t];
        int base = carry;
        if (c + t < n) { rowstart[c + t] = base + incl - v; cursor[c + t] = base + incl - v; }
        __syncthreads();
        if (t == 1023) carry = base + incl;
        __syncthreads();
    }
    if (t == 0) rowstart[n] = carry;
}

__global__ void fill_kernel(const int* __restrict__ src, const int* __restrict__ dst,
                            const int* __restrict__ et, int* __restrict__ cursor,
                            unsigned* __restrict__ csr_val)
{
    int e = blockIdx.x * blockDim.x + threadIdx.x;
    if (e >= EE) return;
    int d = dst[e];
    int pos = atomicAdd(&cursor[d], 1);
    csr_val[pos] = (unsigned)src[e] | ((unsigned)et[e] << 16);
}

// ---- fused attention-softmax aggregation: wave per dst node ----
__global__ void csr_agg_kernel(const unsigned* __restrict__ csr_val,
                               const int* __restrict__ rowstart,
                               const float* __restrict__ s_i, const float* __restrict__ s_j,
                               const float* __restrict__ rsv,
                               const float* __restrict__ Wx, float* __restrict__ agg)
{
    int t = threadIdx.x; int w = t >> 6, l = t & 63;
    int node = blockIdx.x * 4 + w; if (node >= NN) return;
    int start = rowstart[node], end = rowstart[node + 1];
    float r0 = rsv[0], r1 = rsv[1], r2 = rsv[2];
    float si = s_i[node];

    float m = -INFINITY;
    for (int i = start + l; i < end; i += 64) {
        unsigned v = csr_val[i];
        int s = v & 0xFFFF; int et = v >> 16;
        float rr = (et == 0) ? r0 : ((et == 1) ? r1 : r2);
        float lg = si + s_j[s] + rr;
        lg = (lg >= 0.f) ? lg : 0.2f * lg;
        m = fmaxf(m, lg);
    }
    for (int off = 32; off; off >>= 1) m = fmaxf(m, __shfl_down(m, off));
    m = __shfl(m, 0);

    float a0 = 0.f, a1 = 0.f, a2 = 0.f, a3 = 0.f, ssum = 0.f;
    for (int c = start; c < end; c += 64) {
        int nchunk = min(64, end - c);
        float wgt = 0.f; int sidx = 0;
        if (l < nchunk) {
            unsigned v = csr_val[c + l];
            sidx = v & 0xFFFF; int et = v >> 16;
            float rr = (et == 0) ? r0 : ((et == 1) ? r1 : r2);
            float lg = si + s_j[sidx] + rr;
            lg = (lg >= 0.f) ? lg : 0.2f * lg;
            wgt = expf(lg - m);
            ssum += wgt;
        }
        for (int j = 0; j < nchunk; j++) {
            float wj = __shfl(wgt, j);
            int sj = __shfl(sidx, j);
            const float* wr = Wx + (size_t)sj * HID;
            a0 += wj * wr[l];
            a1 += wj * wr[l + 64];
            a2 += wj * wr[l + 128];
            a3 += wj * wr[l + 192];
        }
    }
    for (int off = 32; off; off >>= 1) ssum += __shfl_down(ssum, off);
    ssum = __shfl(ssum, 0);
    float inv = 1.f / (ssum + 1e-16f);
    float* ar = agg + (size_t)node * HID;
    ar[l] = a0 * inv; ar[l + 64] = a1 * inv; ar[l + 128] = a2 * inv; ar[l + 192] = a3 * inv;
}

// row-L2-normalize a split (hi,lo) pair in place
__global__ void rownorm_split(ushort* __restrict__ hi, ushort* __restrict__ lo, int n)
{
    int t = threadIdx.x; int w = t >> 6, l = t & 63;
    int m = blockIdx.x * 4 + w; if (m >= n) return;
    size_t base = (size_t)m * HID;
    float vals[4]; float q = 0.f;
#pragma unroll
    for (int i = 0; i < 4; i++) {
        vals[i] = bf2f(hi[base + l + 64 * i]) + bf2f(lo[base + l + 64 * i]);
        q += vals[i] * vals[i];
    }
    for (int off = 32; off; off >>= 1) q += __shfl_down(q, off);
    q = __shfl(q, 0);
    float inv = 1.f / fmaxf(sqrtf(q), 1e-12f);
#pragma unroll
    for (int i = 0; i < 4; i++) {
        float nv = vals[i] * inv;
        ushort h = f2bf(nv);
        hi[base + l + 64 * i] = h;
        lo[base + l + 64 * i] = f2bf(nv - bf2f(h));
    }
}

// ---------------------------------------------------------------------------
// MoE gating (fp32)
// ---------------------------------------------------------------------------
__global__ void moe_gate_kernel(const float* __restrict__ xv, const float* __restrict__ gate_w,
                                const float* __restrict__ noise_w, const float* __restrict__ eps,
                                float* __restrict__ comb, float* __restrict__ tmpsum)
{
    __shared__ float part[4];
    int t = threadIdx.x; int w = t >> 6, l = t & 63;
    if (t < 4) part[t] = 0.f;
    __syncthreads();
    int b = blockIdx.x * 4 + w;
    const float* xr = xv + (size_t)b * OUT_D;
    float x0 = xr[l], x1 = xr[l + 64];
    float dots[5];
#pragma unroll
    for (int e = 0; e < 4; e++) {
        const float* gw = gate_w + e * OUT_D;
        float v = x0 * gw[l] + x1 * gw[l + 64];
        for (int off = 32; off; off >>= 1) v += __shfl_down(v, off);
        dots[e] = v;
    }
    {
        float v = x0 * noise_w[l] + x1 * noise_w[l + 64];
        for (int off = 32; off; off >>= 1) v += __shfl_down(v, off);
        dots[4] = v;
    }
    if (l == 0) {
        float xg = dots[4];
        float nsd = (xg > 20.f) ? xg : log1pf(expf(xg));
        float hv[4];
#pragma unroll
        for (int e = 0; e < 4; e++) hv[e] = dots[e] + eps[(size_t)b * 4 + e] * nsd;
        int i1 = 0;
        for (int e = 1; e < 4; e++) if (hv[e] < hv[i1]) i1 = e;
        int i2 = -1;
        for (int e = 0; e < 4; e++) { if (e == i1) continue; if (i2 < 0 || hv[e] < hv[i2]) i2 = e; }
        int k1 = -1, k2 = -1;
        for (int e = 0; e < 4; e++) { if (e != i1 && e != i2) { if (k1 < 0) k1 = e; else k2 = e; } }
        float mm = fmaxf(hv[k1], hv[k2]);
        float e1 = expf(hv[k1] - mm), e2 = expf(hv[k2] - mm);
        float s = e1 + e2;
        float L[4] = {0.f, 0.f, 0.f, 0.f};
        L[k1] = e1 / s; L[k2] = e2 / s;
#pragma unroll
        for (int e = 0; e < 4; e++) comb[(size_t)b * 4 + e] = L[e];
        atomicAdd(&part[k1], L[k1]);
        atomicAdd(&part[k2], L[k2]);
    }
    __syncthreads();
    if (t < 4) atomicAdd(&tmpsum[t], part[t]);
}

__global__ void moe_combine_kernel(const float* __restrict__ eo, const float* __restrict__ comb,
                                   float* __restrict__ zout)
{
    int idx = blockIdx.x * blockDim.x + threadIdx.x;
    if (idx >= BB * OUT_D) return;
    int b = idx >> 7, o = idx & 127;
    const size_t S = (size_t)BB * OUT_D;
    float v = comb[b * 4 + 0] * eo[idx] + comb[b * 4 + 1] * eo[idx + S]
            + comb[b * 4 + 2] * eo[idx + 2 * S] + comb[b * 4 + 3] * eo[idx + 3 * S];
    zout[(size_t)b * (3 * OUT_D) + o] = v;
}

__global__ void loss_kernel(const float* __restrict__ tmpsum, float* __restrict__ out)
{
    if (threadIdx.x == 0 && blockIdx.x == 0) {
        float total = 0.f;
        for (int v = 0; v < 3; v++) {
            const float* tp = tmpsum + v * 4;
            float mean = (tp[0] + tp[1] + tp[2] + tp[3]) * 0.25f;
            float var = 0.f;
            for (int e = 0; e < 4; e++) { float d = tp[e] - mean; var += d * d; }
            var /= 3.f;
            float r = sqrtf(var) / mean;
            total += r * r;
        }
        out[0] = total;
    }
}

// ---------------------------------------------------------------------------
// Transformer small kernels
// ---------------------------------------------------------------------------
__global__ void attn_kernel(const float* __restrict__ qkv, float* __restrict__ o)
{
    int t = threadIdx.x;
    int half = t >> 5;
    int d = t & 31;
    int task = blockIdx.x * 8 + half;   // b*4 + h
    int b = task >> 2, h = task & 3;
    const float* base = qkv + (size_t)b * 3 * 384 + h * 32;
    float q0 = base[d],       q1 = base[384 + d],       q2 = base[768 + d];
    float k0 = base[128 + d], k1 = base[384 + 128 + d], k2 = base[768 + 128 + d];
    float v0 = base[256 + d], v1 = base[384 + 256 + d], v2 = base[768 + 256 + d];
    float s[3][3];
    s[0][0] = q0 * k0; s[0][1] = q0 * k1; s[0][2] = q0 * k2;
    s[1][0] = q1 * k0; s[1][1] = q1 * k1; s[1][2] = q1 * k2;
    s[2][0] = q2 * k0; s[2][1] = q2 * k1; s[2][2] = q2 * k2;
#pragma unroll
    for (int i = 0; i < 3; i++)
#pragma unroll
        for (int j = 0; j < 3; j++) {
            float v = s[i][j];
            for (int off = 16; off; off >>= 1) v += __shfl_xor(v, off, 32);
            s[i][j] = v;
        }
    const float scale = 0.17677669529663687f;
    float outv[3];
#pragma unroll
    for (int i = 0; i < 3; i++) {
        float a0 = s[i][0] * scale, a1 = s[i][1] * scale, a2 = s[i][2] * scale;
        float m = fmaxf(a0, fmaxf(a1, a2));
        float e0 = expf(a0 - m), e1 = expf(a1 - m), e2 = expf(a2 - m);
        float inv = 1.f / (e0 + e1 + e2);
        outv[i] = (e0 * v0 + e1 * v1 + e2 * v2) * inv;
    }
    float* ob = o + (size_t)b * 3 * 128 + h * 32;
    ob[d] = outv[0]; ob[128 + d] = outv[1]; ob[256 + d] = outv[2];
}

__global__ void ln_residual_kernel(float* __restrict__ x, const float* __restrict__ add,
                                   const float* __restrict__ g, const float* __restrict__ bta, int M)
{
    int t = threadIdx.x; int w = t >> 6, l = t & 63;
    int row = blockIdx.x * 4 + w; if (row >= M) return;
    float* xr = x + (size_t)row * 128;
    const float* ar = add + (size_t)row * 128;
    float v0 = xr[l] + ar[l], v1 = xr[l + 64] + ar[l + 64];
    float s = v0 + v1;
    for (int off = 32; off; off >>= 1) s += __shfl_down(s, off);
    s = __shfl(s, 0);
    float mu = s * (1.f / 128.f);
    float d0 = v0 - mu, d1 = v1 - mu;
    float q = d0 * d0 + d1 * d1;
    for (int off = 32; off; off >>= 1) q += __shfl_down(q, off);
    q = __shfl(q, 0);
    float inv = rsqrtf(q * (1.f / 128.f) + 1e-5f);
    xr[l]      = d0 * inv * g[l] + bta[l];
    xr[l + 64] = d1 * inv * g[l + 64] + bta[l + 64];
}

__global__ void clf_kernel(const float* __restrict__ z, const float* __restrict__ w,
                           const float* __restrict__ b, float* __restrict__ out)
{
    int t = threadIdx.x; int wv = t >> 6, l = t & 63;
    int row = blockIdx.x * 4 + wv; if (row >= BB) return;
    const float* zr = z + (size_t)row * 384;
    float v0 = 0.f, v1 = 0.f;
    for (int i = l; i < 384; i += 64) {
        float zz = zr[i];
        v0 += zz * w[i];
        v1 += zz * w[384 + i];
    }
    for (int off = 32; off; off >>= 1) { v0 += __shfl_down(v0, off); v1 += __shfl_down(v1, off); }
    if (l == 0) { out[row * 2] = v0 + b[0]; out[row * 2 + 1] = v1 + b[1]; }
}

// ---------------------------------------------------------------------------
// Orchestration
// ---------------------------------------------------------------------------
extern "C" void kernel_launch(void* const* d_in, const int* in_sizes, int n_in,
                              void* d_out, int out_size, void* d_ws, size_t ws_size,
                              hipStream_t stream)
{
    const float* x         = (const float*)d_in[0];
    const float* noise     = (const float*)d_in[1];
    const float* g_lin1_w  = (const float*)d_in[2];
    const float* g_lin1_b  = (const float*)d_in[3];
    const float* conv_W    = (const float*)d_in[4];
    const float* conv_Wr   = (const float*)d_in[5];
    const float* conv_a    = (const float*)d_in[6];
    const float* conv_Wres = (const float*)d_in[7];
    const float* conv_rel  = (const float*)d_in[8];
    const float* g_lin2_w  = (const float*)d_in[9];
    const float* g_lin2_b  = (const float*)d_in[10];
    const float* te_w      = (const float*)d_in[11];
    const float* te_b      = (const float*)d_in[12];
    const float* me_w1     = (const float*)d_in[13];
    const float* me_b1     = (const float*)d_in[14];
    const float* me_w2     = (const float*)d_in[15];
    const float* me_b2     = (const float*)d_in[16];
    const float* moe_gate_w  = (const float*)d_in[17];
    const float* moe_noise_w = (const float*)d_in[18];
    const float* moe_w1    = (const float*)d_in[19];
    const float* moe_b1    = (const float*)d_in[20];
    const float* moe_w2    = (const float*)d_in[21];
    const float* moe_b2    = (const float*)d_in[22];
    const float* tf_qkv_w  = (const float*)d_in[23];
    const float* tf_qkv_b  = (const float*)d_in[24];
    const float* tf_out_w  = (const float*)d_in[25];
    const float* tf_out_b  = (const float*)d_in[26];
    const float* tf_ln1_g  = (const float*)d_in[27];
    const float* tf_ln1_b  = (const float*)d_in[28];
    const float* tf_ff1_w  = (const float*)d_in[29];
    const float* tf_ff1_b  = (const float*)d_in[30];
    const float* tf_ff2_w  = (const float*)d_in[31];
    const float* tf_ff2_b  = (const float*)d_in[32];
    const float* tf_ln2_g  = (const float*)d_in[33];
    const float* tf_ln2_b  = (const float*)d_in[34];
    const float* clf_w     = (const float*)d_in[35];
    const float* clf_b     = (const float*)d_in[36];
    const int*   edge_index = (const int*)d_in[37];
    const int*   edge_type  = (const int*)d_in[38];

    float* ws = (float*)d_ws;

    // Arena (float offsets)
    const size_t F_A = 0;
    const size_t F_B = 10240000;
    const size_t F_C = 22822912;
    const size_t F_D = 33062912;
    const size_t F_M = 43302912;
    const size_t F_X = 44200000;

    ushort* hAhi  = (ushort*)(ws + F_A);
    ushort* hAlo  = (ushort*)(ws + F_A + 5120000);
    float* qkv    = ws + F_A;
    float* wx     = ws + F_B;
    float* graph  = ws + F_B;
    ushort* ff1bf = (ushort*)(ws + F_B);
    float* agg    = ws + F_C;
    float* x_mh   = ws + F_C;
    ushort* h1bf  = (ushort*)(ws + F_C);
    float* attn_o = ws + F_C;
    float* tmp1   = ws + F_C + 3200000;
    ushort* hBhi  = (ushort*)(ws + F_D);
    ushort* hBlo  = (ushort*)(ws + F_D + 5120000);
    float* z      = ws + F_D;
    float* x_t    = ws + F_D + 3200000;
    float* x_m    = ws + F_D + 4300000;
    float* eo     = ws + F_D + 5400000;

    float* s_i    = ws + F_M;
    float* s_j    = ws + F_M + 40000;
    float* rsv    = ws + F_M + 80000;
    float* comb   = ws + F_M + 80016;
    float* tmpsum = ws + F_M + 112784;
    int* deg      = (int*)(ws + F_M + 120000);
    int* rowstart = (int*)(ws + F_M + 161000);
    int* cursor   = (int*)(ws + F_M + 202000);
    unsigned* csr_val = (unsigned*)(ws + F_M + 242000);

    ushort* xhi  = (ushort*)(ws + F_X);                 // 40000x800
    ushort* xlo  = (ushort*)(ws + F_X + 16000000);
    ushort* wbh  = (ushort*)(ws + F_X + 32000000);      // up to 256x800
    ushort* wbl  = (ushort*)(ws + F_X + 32110000);
    ushort* mhhi = (ushort*)(ws + F_X + 32220000);      // 8192x256
    ushort* mhlo = (ushort*)(ws + F_X + 33280000);

    const int* srcv = edge_index;
    const int* dstv = edge_index + EE;

    // ---- 0. CSR build ----
    hipMemsetAsync(deg, 0, NN * sizeof(int), stream);
    deg_kernel<<<(EE + 255) / 256, 256, 0, stream>>>(dstv, deg);
    scan_kernel<<<1, 1024, 0, stream>>>(deg, rowstart, cursor, NN);
    fill_kernel<<<(EE + 255) / 256, 256, 0, stream>>>(srcv, dstv, edge_type, cursor, csr_val);

    // ---- 1. h = relu(x @ g_lin1_w.T + b) -> split pair A ----
    cvt(x, XDIM, XDIM, xhi, xlo, NN, 800, stream);
    cvt(g_lin1_w, XDIM, XDIM, wbh, wbl, HID, 800, stream);
    m128_launch<1, 0, 1>(xhi, xlo, 800, wbh, wbl, 800, g_lin1_b, nullptr,
                         nullptr, hAhi, hAlo, NN, HID, 800, stream);

    // ---- 2. two HGN layers (pair ping-pong A->B->A) ----
    ushort *inhi = hAhi, *inlo = hAlo, *outhi = hBhi, *outlo = hBlo;
    for (int layer = 0; layer < 2; layer++) {
        const float* W    = conv_W    + (size_t)layer * HID * HID;
        const float* Wr   = conv_Wr   + (size_t)layer * HID * REL_D;
        const float* a    = conv_a    + (size_t)layer * 3 * HID;
        const float* Wres = conv_Wres + (size_t)layer * HID * HID;
        const float* rel  = conv_rel  + (size_t)layer * NET_T * REL_D;

        cvt(W, HID, HID, wbh, wbl, HID, HID, stream);
        m128_launch<0, 0, 0>(inhi, inlo, HID, wbh, wbl, HID, nullptr, nullptr,
                             wx, nullptr, nullptr, NN, HID, HID, stream);
        sisj_kernel<<<NN / 4, 256, 0, stream>>>(wx, a, s_i, s_j, NN);
        rs_kernel<<<NET_T, 256, 0, stream>>>(Wr, rel, a + 2 * HID, rsv);
        csr_agg_kernel<<<NN / 4, 256, 0, stream>>>(csr_val, rowstart, s_i, s_j, rsv, wx, agg);
        cvt(Wres, HID, HID, wbh, wbl, HID, HID, stream);
        m128_launch<2, 1, 1>(inhi, inlo, HID, wbh, wbl, HID, nullptr, agg,
                             nullptr, outhi, outlo, NN, HID, HID, stream);
        ushort* th = inhi; inhi = outhi; outhi = th;
        ushort* tl = inlo; inlo = outlo; outlo = tl;
    }
    rownorm_split<<<NN / 4, 256, 0, stream>>>(inhi, inlo, NN);

    // ---- 3. graph = relu(h2 @ g_lin2.T + b) ----
    cvt(g_lin2_w, HID, HID, wbh, wbl, OUT_D, HID, stream);
    m128_launch<1, 0, 0>(inhi, inlo, HID, wbh, wbl, HID, g_lin2_b, nullptr,
                         graph, nullptr, nullptr, NN, OUT_D, HID, stream);

    // ---- 4. view encoders ----
    cvt(te_w, IN_DIM, IN_DIM, wbh, wbl, OUT_D, IN_DIM, stream);
    m128_launch<1, 0, 0>(xhi, xlo, 800, wbh, wbl, IN_DIM, te_b, nullptr,
                         x_t, nullptr, nullptr, BB, OUT_D, IN_DIM, stream);
    launch_gemm(1, x + IN_DIM, XDIM, me_w1, me_b1, nullptr, x_mh, BB, HID, META_DIM, stream);
    cvt(x_mh, HID, HID, mhhi, mhlo, BB, HID, stream);
    cvt(me_w2, HID, HID, wbh, wbl, OUT_D, HID, stream);
    m128_launch<1, 0, 0>(mhhi, mhlo, HID, wbh, wbl, HID, me_b2, nullptr,
                         x_m, nullptr, nullptr, BB, OUT_D, HID, stream);

    // ---- 5. MoE per view: fp32 gate, bf16 MFMA experts ----
    hipMemsetAsync(tmpsum, 0, 16 * sizeof(float), stream);
    const float* xvs[3] = { graph, x_t, x_m };
    for (int v = 0; v < 3; v++) {
        const float* xv = xvs[v];
        moe_gate_kernel<<<BB / 4, 256, 0, stream>>>(
            xv, moe_gate_w + (size_t)v * NEXP * OUT_D, moe_noise_w + (size_t)v * OUT_D,
            noise + (size_t)v * BB * NEXP, comb, tmpsum + v * 4);
        mfma_launch<1, 0, 1>(xv, 0,
                             moe_w1 + (size_t)v * 4 * FF_D * OUT_D, (size_t)FF_D * OUT_D,
                             moe_b1 + (size_t)v * 4 * FF_D, FF_D,
                             h1bf, (size_t)BB * FF_D,
                             BB, FF_D, OUT_D, 4, stream);
        mfma_launch<0, 1, 0>(h1bf, (size_t)BB * FF_D,
                             moe_w2 + (size_t)v * 4 * OUT_D * FF_D, (size_t)OUT_D * FF_D,
                             moe_b2 + (size_t)v * 4 * OUT_D, OUT_D,
                             eo, (size_t)BB * OUT_D,
                             BB, OUT_D, FF_D, 4, stream);
        moe_combine_kernel<<<(BB * OUT_D) / 256, 256, 0, stream>>>(eo, comb, z + v * OUT_D);
    }

    // ---- 6. transformer x4 on z (24576,128) ----
    const int MT = BB * 3;
    for (int li = 0; li < NLAY; li++) {
        mfma_launch<0, 0, 0>(z, 0, tf_qkv_w + (size_t)li * 384 * 128, 0,
                             tf_qkv_b + li * 384, 0, qkv, 0, MT, 384, 128, 1, stream);
        attn_kernel<<<(BB * 4) / 8, 256, 0, stream>>>(qkv, attn_o);
        mfma_launch<0, 0, 0>(attn_o, 0, tf_out_w + (size_t)li * 128 * 128, 0,
                             tf_out_b + li * 128, 0, tmp1, 0, MT, 128, 128, 1, stream);
        ln_residual_kernel<<<MT / 4, 256, 0, stream>>>(z, tmp1, tf_ln1_g + li * 128, tf_ln1_b + li * 128, MT);
        mfma_launch<1, 0, 1>(z, 0, tf_ff1_w + (size_t)li * 512 * 128, 0,
                             tf_ff1_b + li * 512, 0, ff1bf, 0, MT, 512, 128, 1, stream);
        mfma_launch<0, 1, 0>(ff1bf, 0, tf_ff2_w + (size_t)li * 128 * 512, 0,
                             tf_ff2_b + li * 128, 0, tmp1, 0, MT, 128, 512, 1, stream);
        ln_residual_kernel<<<MT / 4, 256, 0, stream>>>(z, tmp1, tf_ln2_g + li * 128, tf_ln2_b + li * 128, MT);
    }

    // ---- 7. classifier + loss ----
    clf_kernel<<<BB / 4, 256, 0, stream>>>(z, clf_w, clf_b, (float*)d_out);
    loss_kernel<<<1, 64, 0, stream>>>(tmpsum, (float*)d_out + BB * 2);
}

// Round 6
// 1718.669 us; speedup vs baseline: 1.1273x; 1.0922x over previous
//
#include <hip/hip_runtime.h>
#include <hip/hip_bf16.h>
#include <math.h>

// Problem constants
#define NN 40000
#define EE 640000
#define BB 8192
#define IN_DIM 768
#define META_DIM 6
#define XDIM 774      // IN+META
#define HID 256
#define OUT_D 128
#define NEXP 4
#define NET_T 3
#define REL_D 200
#define NLAY 4
#define FF_D 512

typedef __attribute__((ext_vector_type(8))) short short8;
typedef __attribute__((ext_vector_type(4))) float f32x4;

__device__ __forceinline__ ushort f2bf(float f) {
    union { float f; unsigned u; } a; a.f = f;
    unsigned u = a.u;
    unsigned r = (u + 0x7FFFu + ((u >> 16) & 1u)) >> 16;  // RNE
    return (ushort)r;
}
__device__ __forceinline__ float bf2f(ushort h) {
    union { unsigned u; float f; } a; a.u = ((unsigned)h) << 16;
    return a.f;
}
__device__ __forceinline__ unsigned packsplit(float v) {
    ushort h = f2bf(v);
    ushort lo = f2bf(v - bf2f(h));
    return ((unsigned)h << 16) | lo;
}

// ---------------------------------------------------------------------------
// fp32 -> packed (hi<<16|lo) split with K padding.
// ---------------------------------------------------------------------------
__global__ void cvt_pack_kernel(const float* __restrict__ src, int ldsrc, int Kreal,
                                unsigned* __restrict__ pk, int R, int ldp)
{
    size_t i = (size_t)blockIdx.x * blockDim.x + threadIdx.x;
    size_t total = (size_t)R * ldp;
    if (i >= total) return;
    int col = (int)(i % ldp);
    int row = (int)(i / ldp);
    float v = (col < Kreal) ? src[(size_t)row * ldsrc + col] : 0.f;
    pk[i] = packsplit(v);
}

static void cvt_pack(const float* src, int ldsrc, int Kreal, unsigned* pk,
                     int R, int ldp, hipStream_t s)
{
    size_t total = (size_t)R * ldp;
    cvt_pack_kernel<<<(int)((total + 255) / 256), 256, 0, s>>>(src, ldsrc, Kreal, pk, R, ldp);
}

// ---------------------------------------------------------------------------
// Split-bf16 (3xMFMA) fp32-precision GEMM, 128x128 tile, software-pipelined.
// A: packed uint (hi<<16|lo). B: fp32 (in-kernel split) or packed.
// N%128==0, K%32==0 (via padded lda/ldb where needed). M arbitrary.
// ACT: 0=none,1=relu,2=elu. HAS_RES: +res. OUT_SPLIT: write packed pair.
// ---------------------------------------------------------------------------
template<int ACT, int HAS_RES, int OUT_SPLIT, int B_PACKED>
__global__ __launch_bounds__(256) void mfma3_128(
    const unsigned* __restrict__ Ap, int lda,
    const void* __restrict__ Bp, int ldb,
    const float* __restrict__ bias, const float* __restrict__ res,
    float* __restrict__ C, unsigned* __restrict__ Cpk,
    int M, int Nn, int K)
{
    __shared__ __align__(16) ushort Ash[128 * 40];
    __shared__ __align__(16) ushort Asl[128 * 40];
    __shared__ __align__(16) ushort Bsh[128 * 40];
    __shared__ __align__(16) ushort Bsl[128 * 40];

    const float*    Bf = (const float*)Bp;
    const unsigned* Bk = (const unsigned*)Bp;

    int bn = blockIdx.x * 128;
    int bm = blockIdx.y * 128;
    int t = threadIdx.x;
    int wave = t >> 6, lane = t & 63;
    int wm = wave & 1, wn = wave >> 1;
    int quad = lane >> 4, r = lane & 15;

    // staging coordinates: per thread 2 chunks of 8 columns
    int arow0 = t >> 2,           ac80 = t & 3;
    int arow1 = (t + 256) >> 2,   ac81 = t & 3;   // (t+256)&3 == t&3

    uint4 apre[2][2];
    uint4 bprek[2][2];
    float4 bpref[2][2];

    auto loadA = [&](int k0) {
        int g0 = bm + arow0; if (g0 > M - 1) g0 = M - 1;
        int g1 = bm + arow1; if (g1 > M - 1) g1 = M - 1;
        const unsigned* p0 = Ap + (size_t)g0 * lda + k0 + ac80 * 8;
        const unsigned* p1 = Ap + (size_t)g1 * lda + k0 + ac81 * 8;
        apre[0][0] = *(const uint4*)p0; apre[0][1] = *(const uint4*)(p0 + 4);
        apre[1][0] = *(const uint4*)p1; apre[1][1] = *(const uint4*)(p1 + 4);
    };
    auto loadB = [&](int k0) {
        if (B_PACKED) {
            const unsigned* p0 = Bk + (size_t)(bn + arow0) * ldb + k0 + ac80 * 8;
            const unsigned* p1 = Bk + (size_t)(bn + arow1) * ldb + k0 + ac81 * 8;
            bprek[0][0] = *(const uint4*)p0; bprek[0][1] = *(const uint4*)(p0 + 4);
            bprek[1][0] = *(const uint4*)p1; bprek[1][1] = *(const uint4*)(p1 + 4);
        } else {
            const float* p0 = Bf + (size_t)(bn + arow0) * ldb + k0 + ac80 * 8;
            const float* p1 = Bf + (size_t)(bn + arow1) * ldb + k0 + ac81 * 8;
            bpref[0][0] = *(const float4*)p0; bpref[0][1] = *(const float4*)(p0 + 4);
            bpref[1][0] = *(const float4*)p1; bpref[1][1] = *(const float4*)(p1 + 4);
        }
    };
    auto storeTiles = [&]() {
#pragma unroll
        for (int i = 0; i < 2; i++) {
            int row = i ? arow1 : arow0, c8 = i ? ac81 : ac80;
            unsigned u[8] = {apre[i][0].x, apre[i][0].y, apre[i][0].z, apre[i][0].w,
                             apre[i][1].x, apre[i][1].y, apre[i][1].z, apre[i][1].w};
            short8 hi, lo;
#pragma unroll
            for (int e = 0; e < 8; e++) { hi[e] = (short)(u[e] >> 16); lo[e] = (short)(u[e] & 0xFFFFu); }
            *(short8*)&Ash[row * 40 + c8 * 8] = hi;
            *(short8*)&Asl[row * 40 + c8 * 8] = lo;
        }
#pragma unroll
        for (int i = 0; i < 2; i++) {
            int row = i ? arow1 : arow0, c8 = i ? ac81 : ac80;
            short8 hi, lo;
            if (B_PACKED) {
                unsigned u[8] = {bprek[i][0].x, bprek[i][0].y, bprek[i][0].z, bprek[i][0].w,
                                 bprek[i][1].x, bprek[i][1].y, bprek[i][1].z, bprek[i][1].w};
#pragma unroll
                for (int e = 0; e < 8; e++) { hi[e] = (short)(u[e] >> 16); lo[e] = (short)(u[e] & 0xFFFFu); }
            } else {
                float f[8] = {bpref[i][0].x, bpref[i][0].y, bpref[i][0].z, bpref[i][0].w,
                              bpref[i][1].x, bpref[i][1].y, bpref[i][1].z, bpref[i][1].w};
#pragma unroll
                for (int e = 0; e < 8; e++) {
                    ushort h = f2bf(f[e]);
                    hi[e] = (short)h;
                    lo[e] = (short)f2bf(f[e] - bf2f(h));
                }
            }
            *(short8*)&Bsh[row * 40 + c8 * 8] = hi;
            *(short8*)&Bsl[row * 40 + c8 * 8] = lo;
        }
    };

    f32x4 acc[4][4];
#pragma unroll
    for (int i = 0; i < 4; i++)
#pragma unroll
        for (int j = 0; j < 4; j++) acc[i][j] = (f32x4){0.f, 0.f, 0.f, 0.f};

    loadA(0); loadB(0);
    for (int k0 = 0; k0 < K; k0 += 32) {
        storeTiles();
        __syncthreads();
        if (k0 + 32 < K) { loadA(k0 + 32); loadB(k0 + 32); }

        short8 ah[4], al[4];
#pragma unroll
        for (int i = 0; i < 4; i++) {
            int ro = (wm * 64 + i * 16 + r) * 40 + quad * 8;
            ah[i] = *(const short8*)&Ash[ro];
            al[i] = *(const short8*)&Asl[ro];
        }
#pragma unroll
        for (int j = 0; j < 4; j++) {
            int ro = (wn * 64 + j * 16 + r) * 40 + quad * 8;
            short8 bh = *(const short8*)&Bsh[ro];
            short8 bl = *(const short8*)&Bsl[ro];
#pragma unroll
            for (int i = 0; i < 4; i++)
                acc[i][j] = __builtin_amdgcn_mfma_f32_16x16x32_bf16(ah[i], bh, acc[i][j], 0, 0, 0);
#pragma unroll
            for (int i = 0; i < 4; i++)
                acc[i][j] = __builtin_amdgcn_mfma_f32_16x16x32_bf16(ah[i], bl, acc[i][j], 0, 0, 0);
#pragma unroll
            for (int i = 0; i < 4; i++)
                acc[i][j] = __builtin_amdgcn_mfma_f32_16x16x32_bf16(al[i], bh, acc[i][j], 0, 0, 0);
        }
        __syncthreads();
    }

    // epilogue
#pragma unroll
    for (int j = 0; j < 4; j++) {
        int col = bn + wn * 64 + j * 16 + r;
        float bc = bias ? bias[col] : 0.f;
#pragma unroll
        for (int i = 0; i < 4; i++) {
#pragma unroll
            for (int reg = 0; reg < 4; reg++) {
                int row = bm + wm * 64 + i * 16 + quad * 4 + reg;
                if (row >= M) continue;
                float v = acc[i][j][reg] + bc;
                if (HAS_RES) v += res[(size_t)row * Nn + col];
                if (ACT == 1) v = fmaxf(v, 0.f);
                else if (ACT == 2) v = (v > 0.f) ? v : expm1f(v);
                if (OUT_SPLIT) Cpk[(size_t)row * Nn + col] = packsplit(v);
                else           C[(size_t)row * Nn + col] = v;
            }
        }
    }
}

template<int ACT, int HAS_RES, int OUT_SPLIT, int B_PACKED>
static void m128_launch(const unsigned* Ap, int lda, const void* Bp, int ldb,
                        const float* bias, const float* res,
                        float* C, unsigned* Cpk,
                        int M, int Nn, int K, hipStream_t s)
{
    dim3 grid(Nn / 128, (M + 127) / 128);
    mfma3_128<ACT, HAS_RES, OUT_SPLIT, B_PACKED><<<grid, 256, 0, s>>>(
        Ap, lda, Bp, ldb, bias, res, C, Cpk, M, Nn, K);
}

// ---------------------------------------------------------------------------
// fp32 tiled GEMM (tiny me_w1 only, K=6)
// ---------------------------------------------------------------------------
template<int ACT>
__global__ void gemm_kernel(const float* __restrict__ A, int lda,
                            const float* __restrict__ Bw,
                            const float* __restrict__ bias,
                            const float* __restrict__ res,
                            float* __restrict__ C, int M, int Nn, int K)
{
    __shared__ float As[16][68];
    __shared__ float Bs[16][68];
    int bm = blockIdx.y * 64, bn = blockIdx.x * 64;
    int t = threadIdx.x;
    int tx = t & 15, ty = t >> 4;
    float acc[4][4] = {{0.f}};

    for (int k0 = 0; k0 < K; k0 += 16) {
#pragma unroll
        for (int i = 0; i < 4; i++) {
            int l = t * 4 + i; int mm = l >> 4, kk = l & 15;
            int gm = bm + mm, gk = k0 + kk;
            As[kk][mm] = (gm < M && gk < K) ? A[(size_t)gm * lda + gk] : 0.f;
        }
#pragma unroll
        for (int i = 0; i < 4; i++) {
            int l = t * 4 + i; int nn = l >> 4, kk = l & 15;
            int gn = bn + nn, gk = k0 + kk;
            Bs[kk][nn] = (gn < Nn && gk < K) ? Bw[(size_t)gn * K + gk] : 0.f;
        }
        __syncthreads();
#pragma unroll
        for (int kk = 0; kk < 16; kk++) {
            float4 a4 = *reinterpret_cast<const float4*>(&As[kk][ty * 4]);
            float4 b4 = *reinterpret_cast<const float4*>(&Bs[kk][tx * 4]);
            float a0[4] = {a4.x, a4.y, a4.z, a4.w};
            float b0[4] = {b4.x, b4.y, b4.z, b4.w};
#pragma unroll
            for (int i = 0; i < 4; i++)
#pragma unroll
                for (int j = 0; j < 4; j++)
                    acc[i][j] += a0[i] * b0[j];
        }
        __syncthreads();
    }
#pragma unroll
    for (int i = 0; i < 4; i++) {
        int gm = bm + ty * 4 + i; if (gm >= M) continue;
#pragma unroll
        for (int j = 0; j < 4; j++) {
            int gn = bn + tx * 4 + j; if (gn >= Nn) continue;
            float v = acc[i][j];
            if (bias) v += bias[gn];
            if (res)  v += res[(size_t)gm * Nn + gn];
            if (ACT == 1) v = fmaxf(v, 0.f);
            else if (ACT == 2) v = (v > 0.f) ? v : expm1f(v);
            C[(size_t)gm * Nn + gn] = v;
        }
    }
}

static void launch_gemm(int act, const float* A, int lda, const float* Bw,
                        const float* bias, const float* res, float* C,
                        int M, int Nn, int K, hipStream_t s)
{
    dim3 grid((Nn + 63) / 64, (M + 63) / 64);
    if (act == 1) gemm_kernel<1><<<grid, 256, 0, s>>>(A, lda, Bw, bias, res, C, M, Nn, K);
    else          gemm_kernel<0><<<grid, 256, 0, s>>>(A, lda, Bw, bias, res, C, M, Nn, K);
}

// ---------------------------------------------------------------------------
// bf16 MFMA GEMM (downstream-of-gate): pipelined. A fp32 or bf16; B fp32.
// Block 128x64 tile, 4 waves of 64x32.
// ---------------------------------------------------------------------------
template<int ACT, int A_BF16, int OUT_BF16>
__global__ __launch_bounds__(256) void mfma_gemm(
    const void* __restrict__ Ap, size_t strideAz,
    const float* __restrict__ Bw, size_t strideBz,
    const float* __restrict__ bias, size_t strideBiasz,
    void* __restrict__ Cp, size_t strideCz,
    int M, int Nn, int K)
{
    __shared__ __align__(16) ushort As[128 * 40];
    __shared__ __align__(16) ushort Bs[64 * 40];

    int z = blockIdx.z;
    const float*  Af  = (const float*)Ap  + (A_BF16 ? 0 : z * strideAz);
    const ushort* Ab  = (const ushort*)Ap + (A_BF16 ? z * strideAz : 0);
    const float*  Bwz = Bw + z * strideBz;
    const float*  bz  = bias ? bias + z * strideBiasz : nullptr;
    float*  Cf = (float*)Cp  + (OUT_BF16 ? 0 : z * strideCz);
    ushort* Cb = (ushort*)Cp + (OUT_BF16 ? z * strideCz : 0);

    int bn = blockIdx.x * 64;
    int bm = blockIdx.y * 128;
    int t = threadIdx.x;
    int wave = t >> 6, lane = t & 63;
    int wm = wave & 1, wn = wave >> 1;
    int quad = lane >> 4, r = lane & 15;

    // A staging: bf16 -> 2 chunks of 8; fp32 -> 4 chunks of 4
    int ar0 = t >> 2, ac0 = t & 3;
    int ar1 = (t + 256) >> 2;
    // B staging: 64x32 -> 256 chunks of 8, one per thread
    int br = t >> 2, bc = t & 3;

    short8 apre_b[2];
    float4 apre_f[4];
    float4 bpre[2];

    auto loadA = [&](int k0) {
        if (A_BF16) {
            apre_b[0] = *(const short8*)(Ab + (size_t)(bm + ar0) * K + k0 + ac0 * 8);
            apre_b[1] = *(const short8*)(Ab + (size_t)(bm + ar1) * K + k0 + ac0 * 8);
        } else {
#pragma unroll
            for (int i = 0; i < 4; i++) {
                int idx = t + i * 256;
                int row = idx >> 3, c4 = idx & 7;
                apre_f[i] = *(const float4*)(Af + (size_t)(bm + row) * K + k0 + c4 * 4);
            }
        }
    };
    auto loadB = [&](int k0) {
        const float* p = Bwz + (size_t)(bn + br) * K + k0 + bc * 8;
        bpre[0] = *(const float4*)p;
        bpre[1] = *(const float4*)(p + 4);
    };
    auto storeTiles = [&]() {
        if (A_BF16) {
            *(short8*)&As[ar0 * 40 + ac0 * 8] = apre_b[0];
            *(short8*)&As[ar1 * 40 + ac0 * 8] = apre_b[1];
        } else {
#pragma unroll
            for (int i = 0; i < 4; i++) {
                int idx = t + i * 256;
                int row = idx >> 3, c4 = idx & 7;
                ushort4 u;
                u.x = f2bf(apre_f[i].x); u.y = f2bf(apre_f[i].y);
                u.z = f2bf(apre_f[i].z); u.w = f2bf(apre_f[i].w);
                *(ushort4*)&As[row * 40 + c4 * 4] = u;
            }
        }
        {
            float f[8] = {bpre[0].x, bpre[0].y, bpre[0].z, bpre[0].w,
                          bpre[1].x, bpre[1].y, bpre[1].z, bpre[1].w};
            short8 hb;
#pragma unroll
            for (int e = 0; e < 8; e++) hb[e] = (short)f2bf(f[e]);
            *(short8*)&Bs[br * 40 + bc * 8] = hb;
        }
    };

    f32x4 acc[4][2];
#pragma unroll
    for (int i = 0; i < 4; i++)
#pragma unroll
        for (int j = 0; j < 2; j++) acc[i][j] = (f32x4){0.f, 0.f, 0.f, 0.f};

    loadA(0); loadB(0);
    for (int k0 = 0; k0 < K; k0 += 32) {
        storeTiles();
        __syncthreads();
        if (k0 + 32 < K) { loadA(k0 + 32); loadB(k0 + 32); }

        short8 af[4];
#pragma unroll
        for (int i = 0; i < 4; i++)
            af[i] = *(const short8*)&As[(wm * 64 + i * 16 + r) * 40 + quad * 8];
#pragma unroll
        for (int j = 0; j < 2; j++) {
            short8 bf = *(const short8*)&Bs[(wn * 32 + j * 16 + r) * 40 + quad * 8];
#pragma unroll
            for (int i = 0; i < 4; i++)
                acc[i][j] = __builtin_amdgcn_mfma_f32_16x16x32_bf16(af[i], bf, acc[i][j], 0, 0, 0);
        }
        __syncthreads();
    }

    float bcol[2];
#pragma unroll
    for (int j = 0; j < 2; j++)
        bcol[j] = bz ? bz[bn + wn * 32 + j * 16 + r] : 0.f;
#pragma unroll
    for (int i = 0; i < 4; i++) {
#pragma unroll
        for (int j = 0; j < 2; j++) {
            int col = bn + wn * 32 + j * 16 + r;
#pragma unroll
            for (int reg = 0; reg < 4; reg++) {
                int row = bm + wm * 64 + i * 16 + quad * 4 + reg;
                float v = acc[i][j][reg] + bcol[j];
                if (ACT == 1) v = fmaxf(v, 0.f);
                if (OUT_BF16) Cb[(size_t)row * Nn + col] = f2bf(v);
                else          Cf[(size_t)row * Nn + col] = v;
            }
        }
    }
}

template<int ACT, int A_BF16, int OUT_BF16>
static void mfma_launch(const void* A, size_t sAz, const float* Bw, size_t sBz,
                        const float* bias, size_t sbz, void* C, size_t sCz,
                        int M, int Nn, int K, int batch, hipStream_t s)
{
    dim3 grid(Nn / 64, M / 128, batch);
    mfma_gemm<ACT, A_BF16, OUT_BF16><<<grid, 256, 0, s>>>(A, sAz, Bw, sBz, bias, sbz, C, sCz, M, Nn, K);
}

// ---------------------------------------------------------------------------
// GNN helper kernels
// ---------------------------------------------------------------------------
__global__ void sisj_kernel(const float* __restrict__ Wx, const float* __restrict__ a,
                            float* __restrict__ s_i, float* __restrict__ s_j, int n)
{
    int t = threadIdx.x; int w = t >> 6, l = t & 63;
    int m = blockIdx.x * 4 + w; if (m >= n) return;
    const float* r = Wx + (size_t)m * HID;
    float v1 = 0.f, v2 = 0.f;
#pragma unroll
    for (int i = 0; i < 4; i++) {
        float xv = r[l + 64 * i];
        v1 += xv * a[l + 64 * i];
        v2 += xv * a[HID + l + 64 * i];
    }
    for (int off = 32; off; off >>= 1) { v1 += __shfl_down(v1, off); v2 += __shfl_down(v2, off); }
    if (l == 0) { s_i[m] = v1; s_j[m] = v2; }
}

__global__ void rs_kernel(const float* __restrict__ Wr, const float* __restrict__ rel,
                          const float* __restrict__ a3, float* __restrict__ rs)
{
    __shared__ float red[256];
    int tt = blockIdx.x; int j = threadIdx.x;
    const float* relr = rel + tt * REL_D;
    const float* wr = Wr + (size_t)j * REL_D;
    float wsum = 0.f;
    for (int k = 0; k < REL_D; k++) wsum += wr[k] * relr[k];
    red[j] = wsum * a3[j];
    __syncthreads();
    for (int s2 = 128; s2; s2 >>= 1) { if (j < s2) red[j] += red[j + s2]; __syncthreads(); }
    if (j == 0) rs[tt] = red[0];
}

// ---- CSR build ----
__global__ void deg_kernel(const int* __restrict__ dst, int* __restrict__ deg)
{
    int e = blockIdx.x * blockDim.x + threadIdx.x;
    if (e < EE) atomicAdd(&deg[dst[e]], 1);
}

// one block of 1024 threads; each thread scans 40 consecutive elements
__global__ void scan_kernel(const int* __restrict__ deg, int* __restrict__ rowstart,
                            int* __restrict__ cursor, int n)
{
    __shared__ int bs[1024];
    int t = threadIdx.x;
    int base = t * 40;
    int loc[40];
    int sum = 0;
#pragma unroll
    for (int i = 0; i < 40; i++) {
        int v = (base + i < n) ? deg[base + i] : 0;
        loc[i] = sum; sum += v;
    }
    bs[t] = sum;
    __syncthreads();
    for (int off = 1; off < 1024; off <<= 1) {
        int x = (t >= off) ? bs[t - off] : 0;
        __syncthreads();
        bs[t] += x;
        __syncthreads();
    }
    int excl = bs[t] - sum;
#pragma unroll
    for (int i = 0; i < 40; i++) {
        if (base + i < n) { int v = excl + loc[i]; rowstart[base + i] = v; cursor[base + i] = v; }
    }
    if (t == 1023) rowstart[n] = bs[1023];
}

__global__ void fill_kernel(const int* __restrict__ src, const int* __restrict__ dst,
                            const int* __restrict__ et, int* __restrict__ cursor,
                            unsigned* __restrict__ csr_val)
{
    int e = blockIdx.x * blockDim.x + threadIdx.x;
    if (e >= EE) return;
    int d = dst[e];
    int pos = atomicAdd(&cursor[d], 1);
    csr_val[pos] = (unsigned)src[e] | ((unsigned)et[e] << 16);
}

// ---- fused attention-softmax aggregation: wave per dst node ----
__global__ void csr_agg_kernel(const unsigned* __restrict__ csr_val,
                               const int* __restrict__ rowstart,
                               const float* __restrict__ s_i, const float* __restrict__ s_j,
                               const float* __restrict__ rsv,
                               const float* __restrict__ Wx, float* __restrict__ agg)
{
    int t = threadIdx.x; int w = t >> 6, l = t & 63;
    int node = blockIdx.x * 4 + w; if (node >= NN) return;
    int start = rowstart[node], end = rowstart[node + 1];
    float r0 = rsv[0], r1 = rsv[1], r2 = rsv[2];
    float si = s_i[node];

    float m = -INFINITY;
    for (int i = start + l; i < end; i += 64) {
        unsigned v = csr_val[i];
        int s = v & 0xFFFF; int et = v >> 16;
        float rr = (et == 0) ? r0 : ((et == 1) ? r1 : r2);
        float lg = si + s_j[s] + rr;
        lg = (lg >= 0.f) ? lg : 0.2f * lg;
        m = fmaxf(m, lg);
    }
    for (int off = 32; off; off >>= 1) m = fmaxf(m, __shfl_down(m, off));
    m = __shfl(m, 0);

    float a0 = 0.f, a1 = 0.f, a2 = 0.f, a3 = 0.f, ssum = 0.f;
    for (int c = start; c < end; c += 64) {
        int nchunk = min(64, end - c);
        float wgt = 0.f; int sidx = 0;
        if (l < nchunk) {
            unsigned v = csr_val[c + l];
            sidx = v & 0xFFFF; int et = v >> 16;
            float rr = (et == 0) ? r0 : ((et == 1) ? r1 : r2);
            float lg = si + s_j[sidx] + rr;
            lg = (lg >= 0.f) ? lg : 0.2f * lg;
            wgt = expf(lg - m);
            ssum += wgt;
        }
        int j = 0;
        for (; j + 4 <= nchunk; j += 4) {
            float w0 = __shfl(wgt, j),     w1 = __shfl(wgt, j + 1);
            float w2 = __shfl(wgt, j + 2), w3 = __shfl(wgt, j + 3);
            int s0 = __shfl(sidx, j),     s1 = __shfl(sidx, j + 1);
            int s2 = __shfl(sidx, j + 2), s3 = __shfl(sidx, j + 3);
            const float* p0 = Wx + (size_t)s0 * HID + l;
            const float* p1 = Wx + (size_t)s1 * HID + l;
            const float* p2 = Wx + (size_t)s2 * HID + l;
            const float* p3 = Wx + (size_t)s3 * HID + l;
            float v00 = p0[0], v01 = p0[64], v02 = p0[128], v03 = p0[192];
            float v10 = p1[0], v11 = p1[64], v12 = p1[128], v13 = p1[192];
            float v20 = p2[0], v21 = p2[64], v22 = p2[128], v23 = p2[192];
            float v30 = p3[0], v31 = p3[64], v32 = p3[128], v33 = p3[192];
            a0 += w0 * v00 + w1 * v10 + w2 * v20 + w3 * v30;
            a1 += w0 * v01 + w1 * v11 + w2 * v21 + w3 * v31;
            a2 += w0 * v02 + w1 * v12 + w2 * v22 + w3 * v32;
            a3 += w0 * v03 + w1 * v13 + w2 * v23 + w3 * v33;
        }
        for (; j < nchunk; j++) {
            float wj = __shfl(wgt, j);
            int sj = __shfl(sidx, j);
            const float* wr = Wx + (size_t)sj * HID + l;
            a0 += wj * wr[0];
            a1 += wj * wr[64];
            a2 += wj * wr[128];
            a3 += wj * wr[192];
        }
    }
    for (int off = 32; off; off >>= 1) ssum += __shfl_down(ssum, off);
    ssum = __shfl(ssum, 0);
    float inv = 1.f / (ssum + 1e-16f);
    float* ar = agg + (size_t)node * HID;
    ar[l] = a0 * inv; ar[l + 64] = a1 * inv; ar[l + 128] = a2 * inv; ar[l + 192] = a3 * inv;
}

// row-L2-normalize a packed pair in place
__global__ void rownorm_pack(unsigned* __restrict__ pk, int n)
{
    int t = threadIdx.x; int w = t >> 6, l = t & 63;
    int m = blockIdx.x * 4 + w; if (m >= n) return;
    size_t base = (size_t)m * HID;
    float vals[4]; float q = 0.f;
#pragma unroll
    for (int i = 0; i < 4; i++) {
        unsigned u = pk[base + l + 64 * i];
        vals[i] = bf2f((ushort)(u >> 16)) + bf2f((ushort)(u & 0xFFFFu));
        q += vals[i] * vals[i];
    }
    for (int off = 32; off; off >>= 1) q += __shfl_down(q, off);
    q = __shfl(q, 0);
    float inv = 1.f / fmaxf(sqrtf(q), 1e-12f);
#pragma unroll
    for (int i = 0; i < 4; i++)
        pk[base + l + 64 * i] = packsplit(vals[i] * inv);
}

// ---------------------------------------------------------------------------
// MoE gating (fp32)
// ---------------------------------------------------------------------------
__global__ void moe_gate_kernel(const float* __restrict__ xv, const float* __restrict__ gate_w,
                                const float* __restrict__ noise_w, const float* __restrict__ eps,
                                float* __restrict__ comb, float* __restrict__ tmpsum)
{
    __shared__ float part[4];
    int t = threadIdx.x; int w = t >> 6, l = t & 63;
    if (t < 4) part[t] = 0.f;
    __syncthreads();
    int b = blockIdx.x * 4 + w;
    const float* xr = xv + (size_t)b * OUT_D;
    float x0 = xr[l], x1 = xr[l + 64];
    float dots[5];
#pragma unroll
    for (int e = 0; e < 4; e++) {
        const float* gw = gate_w + e * OUT_D;
        float v = x0 * gw[l] + x1 * gw[l + 64];
        for (int off = 32; off; off >>= 1) v += __shfl_down(v, off);
        dots[e] = v;
    }
    {
        float v = x0 * noise_w[l] + x1 * noise_w[l + 64];
        for (int off = 32; off; off >>= 1) v += __shfl_down(v, off);
        dots[4] = v;
    }
    if (l == 0) {
        float xg = dots[4];
        float nsd = (xg > 20.f) ? xg : log1pf(expf(xg));
        float hv[4];
#pragma unroll
        for (int e = 0; e < 4; e++) hv[e] = dots[e] + eps[(size_t)b * 4 + e] * nsd;
        int i1 = 0;
        for (int e = 1; e < 4; e++) if (hv[e] < hv[i1]) i1 = e;
        int i2 = -1;
        for (int e = 0; e < 4; e++) { if (e == i1) continue; if (i2 < 0 || hv[e] < hv[i2]) i2 = e; }
        int k1 = -1, k2 = -1;
        for (int e = 0; e < 4; e++) { if (e != i1 && e != i2) { if (k1 < 0) k1 = e; else k2 = e; } }
        float mm = fmaxf(hv[k1], hv[k2]);
        float e1 = expf(hv[k1] - mm), e2 = expf(hv[k2] - mm);
        float s = e1 + e2;
        float L[4] = {0.f, 0.f, 0.f, 0.f};
        L[k1] = e1 / s; L[k2] = e2 / s;
#pragma unroll
        for (int e = 0; e < 4; e++) comb[(size_t)b * 4 + e] = L[e];
        atomicAdd(&part[k1], L[k1]);
        atomicAdd(&part[k2], L[k2]);
    }
    __syncthreads();
    if (t < 4) atomicAdd(&tmpsum[t], part[t]);
}

__global__ void moe_combine_kernel(const float* __restrict__ eo, const float* __restrict__ comb,
                                   float* __restrict__ zout)
{
    int idx = blockIdx.x * blockDim.x + threadIdx.x;
    if (idx >= BB * OUT_D) return;
    int b = idx >> 7, o = idx & 127;
    const size_t S = (size_t)BB * OUT_D;
    float v = comb[b * 4 + 0] * eo[idx] + comb[b * 4 + 1] * eo[idx + S]
            + comb[b * 4 + 2] * eo[idx + 2 * S] + comb[b * 4 + 3] * eo[idx + 3 * S];
    zout[(size_t)b * (3 * OUT_D) + o] = v;
}

__global__ void loss_kernel(const float* __restrict__ tmpsum, float* __restrict__ out)
{
    if (threadIdx.x == 0 && blockIdx.x == 0) {
        float total = 0.f;
        for (int v = 0; v < 3; v++) {
            const float* tp = tmpsum + v * 4;
            float mean = (tp[0] + tp[1] + tp[2] + tp[3]) * 0.25f;
            float var = 0.f;
            for (int e = 0; e < 4; e++) { float d = tp[e] - mean; var += d * d; }
            var /= 3.f;
            float r = sqrtf(var) / mean;
            total += r * r;
        }
        out[0] = total;
    }
}

// ---------------------------------------------------------------------------
// Transformer small kernels
// ---------------------------------------------------------------------------
__global__ void attn_kernel(const float* __restrict__ qkv, float* __restrict__ o)
{
    int t = threadIdx.x;
    int half = t >> 5;
    int d = t & 31;
    int task = blockIdx.x * 8 + half;   // b*4 + h
    int b = task >> 2, h = task & 3;
    const float* base = qkv + (size_t)b * 3 * 384 + h * 32;
    float q0 = base[d],       q1 = base[384 + d],       q2 = base[768 + d];
    float k0 = base[128 + d], k1 = base[384 + 128 + d], k2 = base[768 + 128 + d];
    float v0 = base[256 + d], v1 = base[384 + 256 + d], v2 = base[768 + 256 + d];
    float s[3][3];
    s[0][0] = q0 * k0; s[0][1] = q0 * k1; s[0][2] = q0 * k2;
    s[1][0] = q1 * k0; s[1][1] = q1 * k1; s[1][2] = q1 * k2;
    s[2][0] = q2 * k0; s[2][1] = q2 * k1; s[2][2] = q2 * k2;
#pragma unroll
    for (int i = 0; i < 3; i++)
#pragma unroll
        for (int j = 0; j < 3; j++) {
            float v = s[i][j];
            for (int off = 16; off; off >>= 1) v += __shfl_xor(v, off, 32);
            s[i][j] = v;
        }
    const float scale = 0.17677669529663687f;
    float outv[3];
#pragma unroll
    for (int i = 0; i < 3; i++) {
        float a0 = s[i][0] * scale, a1 = s[i][1] * scale, a2 = s[i][2] * scale;
        float m = fmaxf(a0, fmaxf(a1, a2));
        float e0 = expf(a0 - m), e1 = expf(a1 - m), e2 = expf(a2 - m);
        float inv = 1.f / (e0 + e1 + e2);
        outv[i] = (e0 * v0 + e1 * v1 + e2 * v2) * inv;
    }
    float* ob = o + (size_t)b * 3 * 128 + h * 32;
    ob[d] = outv[0]; ob[128 + d] = outv[1]; ob[256 + d] = outv[2];
}

__global__ void ln_residual_kernel(float* __restrict__ x, const float* __restrict__ add,
                                   const float* __restrict__ g, const float* __restrict__ bta, int M)
{
    int t = threadIdx.x; int w = t >> 6, l = t & 63;
    int row = blockIdx.x * 4 + w; if (row >= M) return;
    float* xr = x + (size_t)row * 128;
    const float* ar = add + (size_t)row * 128;
    float v0 = xr[l] + ar[l], v1 = xr[l + 64] + ar[l + 64];
    float s = v0 + v1;
    for (int off = 32; off; off >>= 1) s += __shfl_down(s, off);
    s = __shfl(s, 0);
    float mu = s * (1.f / 128.f);
    float d0 = v0 - mu, d1 = v1 - mu;
    float q = d0 * d0 + d1 * d1;
    for (int off = 32; off; off >>= 1) q += __shfl_down(q, off);
    q = __shfl(q, 0);
    float inv = rsqrtf(q * (1.f / 128.f) + 1e-5f);
    xr[l]      = d0 * inv * g[l] + bta[l];
    xr[l + 64] = d1 * inv * g[l + 64] + bta[l + 64];
}

__global__ void clf_kernel(const float* __restrict__ z, const float* __restrict__ w,
                           const float* __restrict__ b, float* __restrict__ out)
{
    int t = threadIdx.x; int wv = t >> 6, l = t & 63;
    int row = blockIdx.x * 4 + wv; if (row >= BB) return;
    const float* zr = z + (size_t)row * 384;
    float v0 = 0.f, v1 = 0.f;
    for (int i = l; i < 384; i += 64) {
        float zz = zr[i];
        v0 += zz * w[i];
        v1 += zz * w[384 + i];
    }
    for (int off = 32; off; off >>= 1) { v0 += __shfl_down(v0, off); v1 += __shfl_down(v1, off); }
    if (l == 0) { out[row * 2] = v0 + b[0]; out[row * 2 + 1] = v1 + b[1]; }
}

// ---------------------------------------------------------------------------
// Orchestration
// ---------------------------------------------------------------------------
extern "C" void kernel_launch(void* const* d_in, const int* in_sizes, int n_in,
                              void* d_out, int out_size, void* d_ws, size_t ws_size,
                              hipStream_t stream)
{
    const float* x         = (const float*)d_in[0];
    const float* noise     = (const float*)d_in[1];
    const float* g_lin1_w  = (const float*)d_in[2];
    const float* g_lin1_b  = (const float*)d_in[3];
    const float* conv_W    = (const float*)d_in[4];
    const float* conv_Wr   = (const float*)d_in[5];
    const float* conv_a    = (const float*)d_in[6];
    const float* conv_Wres = (const float*)d_in[7];
    const float* conv_rel  = (const float*)d_in[8];
    const float* g_lin2_w  = (const float*)d_in[9];
    const float* g_lin2_b  = (const float*)d_in[10];
    const float* te_w      = (const float*)d_in[11];
    const float* te_b      = (const float*)d_in[12];
    const float* me_w1     = (const float*)d_in[13];
    const float* me_b1     = (const float*)d_in[14];
    const float* me_w2     = (const float*)d_in[15];
    const float* me_b2     = (const float*)d_in[16];
    const float* moe_gate_w  = (const float*)d_in[17];
    const float* moe_noise_w = (const float*)d_in[18];
    const float* moe_w1    = (const float*)d_in[19];
    const float* moe_b1    = (const float*)d_in[20];
    const float* moe_w2    = (const float*)d_in[21];
    const float* moe_b2    = (const float*)d_in[22];
    const float* tf_qkv_w  = (const float*)d_in[23];
    const float* tf_qkv_b  = (const float*)d_in[24];
    const float* tf_out_w  = (const float*)d_in[25];
    const float* tf_out_b  = (const float*)d_in[26];
    const float* tf_ln1_g  = (const float*)d_in[27];
    const float* tf_ln1_b  = (const float*)d_in[28];
    const float* tf_ff1_w  = (const float*)d_in[29];
    const float* tf_ff1_b  = (const float*)d_in[30];
    const float* tf_ff2_w  = (const float*)d_in[31];
    const float* tf_ff2_b  = (const float*)d_in[32];
    const float* tf_ln2_g  = (const float*)d_in[33];
    const float* tf_ln2_b  = (const float*)d_in[34];
    const float* clf_w     = (const float*)d_in[35];
    const float* clf_b     = (const float*)d_in[36];
    const int*   edge_index = (const int*)d_in[37];
    const int*   edge_type  = (const int*)d_in[38];

    float* ws = (float*)d_ws;

    // Arena (float offsets)
    const size_t F_A = 0;          // hApk (40000x256 uint) / qkv
    const size_t F_B = 10240000;   // wx / graph / ff1(bf16)
    const size_t F_C = 22822912;   // agg / x_mh / h1bf / attn_o+tmp1
    const size_t F_D = 33062912;   // hBpk / z,x_t,x_m,eo
    const size_t F_M = 43302912;   // misc + CSR
    const size_t F_X = 44200000;   // xpk (32M uint), wpk, mhpk

    unsigned* hApk = (unsigned*)(ws + F_A);
    float* qkv    = ws + F_A;
    float* wx     = ws + F_B;
    float* graph  = ws + F_B;
    ushort* ff1bf = (ushort*)(ws + F_B);
    float* agg    = ws + F_C;
    float* x_mh   = ws + F_C;
    ushort* h1bf  = (ushort*)(ws + F_C);
    float* attn_o = ws + F_C;
    float* tmp1   = ws + F_C + 3200000;
    unsigned* hBpk = (unsigned*)(ws + F_D);
    float* z      = ws + F_D;
    float* x_t    = ws + F_D + 3200000;
    float* x_m    = ws + F_D + 4300000;
    float* eo     = ws + F_D + 5400000;

    float* s_i    = ws + F_M;
    float* s_j    = ws + F_M + 40000;
    float* rsv    = ws + F_M + 80000;
    float* comb   = ws + F_M + 80016;
    float* tmpsum = ws + F_M + 112784;
    int* deg      = (int*)(ws + F_M + 120000);
    int* rowstart = (int*)(ws + F_M + 161000);
    int* cursor   = (int*)(ws + F_M + 202000);
    unsigned* csr_val = (unsigned*)(ws + F_M + 242000);

    unsigned* xpk  = (unsigned*)(ws + F_X);              // 40000x800
    unsigned* wpk  = (unsigned*)(ws + F_X + 32000000);   // 256x800
    unsigned* mhpk = (unsigned*)(ws + F_X + 32300000);   // 8192x256

    const int* srcv = edge_index;
    const int* dstv = edge_index + EE;

    // ---- 0. CSR build ----
    hipMemsetAsync(deg, 0, NN * sizeof(int), stream);
    deg_kernel<<<(EE + 255) / 256, 256, 0, stream>>>(dstv, deg);
    scan_kernel<<<1, 1024, 0, stream>>>(deg, rowstart, cursor, NN);
    fill_kernel<<<(EE + 255) / 256, 256, 0, stream>>>(srcv, dstv, edge_type, cursor, csr_val);

    // ---- 1. h = relu(x @ g_lin1_w.T + b) -> packed pair A ----
    cvt_pack(x, XDIM, XDIM, xpk, NN, 800, stream);
    cvt_pack(g_lin1_w, XDIM, XDIM, wpk, HID, 800, stream);
    m128_launch<1, 0, 1, 1>(xpk, 800, wpk, 800, g_lin1_b, nullptr,
                            nullptr, hApk, NN, HID, 800, stream);

    // ---- 2. two HGN layers (packed ping-pong A->B->A) ----
    unsigned *inpk = hApk, *outpk = hBpk;
    for (int layer = 0; layer < 2; layer++) {
        const float* W    = conv_W    + (size_t)layer * HID * HID;
        const float* Wr   = conv_Wr   + (size_t)layer * HID * REL_D;
        const float* a    = conv_a    + (size_t)layer * 3 * HID;
        const float* Wres = conv_Wres + (size_t)layer * HID * HID;
        const float* rel  = conv_rel  + (size_t)layer * NET_T * REL_D;

        m128_launch<0, 0, 0, 0>(inpk, HID, W, HID, nullptr, nullptr,
                                wx, nullptr, NN, HID, HID, stream);
        sisj_kernel<<<NN / 4, 256, 0, stream>>>(wx, a, s_i, s_j, NN);
        rs_kernel<<<NET_T, 256, 0, stream>>>(Wr, rel, a + 2 * HID, rsv);
        csr_agg_kernel<<<NN / 4, 256, 0, stream>>>(csr_val, rowstart, s_i, s_j, rsv, wx, agg);
        m128_launch<2, 1, 1, 0>(inpk, HID, Wres, HID, nullptr, agg,
                                nullptr, outpk, NN, HID, HID, stream);
        unsigned* tp = inpk; inpk = outpk; outpk = tp;
    }
    rownorm_pack<<<NN / 4, 256, 0, stream>>>(inpk, NN);

    // ---- 3. graph = relu(h2 @ g_lin2.T + b) ----
    m128_launch<1, 0, 0, 0>(inpk, HID, g_lin2_w, HID, g_lin2_b, nullptr,
                            graph, nullptr, NN, OUT_D, HID, stream);

    // ---- 4. view encoders ----
    m128_launch<1, 0, 0, 0>(xpk, 800, te_w, IN_DIM, te_b, nullptr,
                            x_t, nullptr, BB, OUT_D, IN_DIM, stream);
    launch_gemm(1, x + IN_DIM, XDIM, me_w1, me_b1, nullptr, x_mh, BB, HID, META_DIM, stream);
    cvt_pack(x_mh, HID, HID, mhpk, BB, HID, stream);
    m128_launch<1, 0, 0, 0>(mhpk, HID, me_w2, HID, me_b2, nullptr,
                            x_m, nullptr, BB, OUT_D, HID, stream);

    // ---- 5. MoE per view: fp32 gate, bf16 MFMA experts ----
    hipMemsetAsync(tmpsum, 0, 16 * sizeof(float), stream);
    const float* xvs[3] = { graph, x_t, x_m };
    for (int v = 0; v < 3; v++) {
        const float* xv = xvs[v];
        moe_gate_kernel<<<BB / 4, 256, 0, stream>>>(
            xv, moe_gate_w + (size_t)v * NEXP * OUT_D, moe_noise_w + (size_t)v * OUT_D,
            noise + (size_t)v * BB * NEXP, comb, tmpsum + v * 4);
        mfma_launch<1, 0, 1>(xv, 0,
                             moe_w1 + (size_t)v * 4 * FF_D * OUT_D, (size_t)FF_D * OUT_D,
                             moe_b1 + (size_t)v * 4 * FF_D, FF_D,
                             h1bf, (size_t)BB * FF_D,
                             BB, FF_D, OUT_D, 4, stream);
        mfma_launch<0, 1, 0>(h1bf, (size_t)BB * FF_D,
                             moe_w2 + (size_t)v * 4 * OUT_D * FF_D, (size_t)OUT_D * FF_D,
                             moe_b2 + (size_t)v * 4 * OUT_D, OUT_D,
                             eo, (size_t)BB * OUT_D,
                             BB, OUT_D, FF_D, 4, stream);
        moe_combine_kernel<<<(BB * OUT_D) / 256, 256, 0, stream>>>(eo, comb, z + v * OUT_D);
    }

    // ---- 6. transformer x4 on z (24576,128) ----
    const int MT = BB * 3;
    for (int li = 0; li < NLAY; li++) {
        mfma_launch<0, 0, 0>(z, 0, tf_qkv_w + (size_t)li * 384 * 128, 0,
                             tf_qkv_b + li * 384, 0, qkv, 0, MT, 384, 128, 1, stream);
        attn_kernel<<<(BB * 4) / 8, 256, 0, stream>>>(qkv, attn_o);
        mfma_launch<0, 0, 0>(attn_o, 0, tf_out_w + (size_t)li * 128 * 128, 0,
                             tf_out_b + li * 128, 0, tmp1, 0, MT, 128, 128, 1, stream);
        ln_residual_kernel<<<MT / 4, 256, 0, stream>>>(z, tmp1, tf_ln1_g + li * 128, tf_ln1_b + li * 128, MT);
        mfma_launch<1, 0, 1>(z, 0, tf_ff1_w + (size_t)li * 512 * 128, 0,
                             tf_ff1_b + li * 512, 0, ff1bf, 0, MT, 512, 128, 1, stream);
        mfma_launch<0, 1, 0>(ff1bf, 0, tf_ff2_w + (size_t)li * 128 * 512, 0,
                             tf_ff2_b + li * 128, 0, tmp1, 0, MT, 128, 512, 1, stream);
        ln_residual_kernel<<<MT / 4, 256, 0, stream>>>(z, tmp1, tf_ln2_g + li * 128, tf_ln2_b + li * 128, MT);
    }

    // ---- 7. classifier + loss ----
    clf_kernel<<<BB / 4, 256, 0, stream>>>(z, clf_w, clf_b, (float*)d_out);
    loss_kernel<<<1, 64, 0, stream>>>(tmpsum, (float*)d_out + BB * 2);
}

// Round 7
// 1520.703 us; speedup vs baseline: 1.2740x; 1.1302x over previous
//
#include <hip/hip_runtime.h>
#include <hip/hip_bf16.h>
#include <math.h>

// Problem constants
#define NN 40000
#define EE 640000
#define BB 8192
#define IN_DIM 768
#define META_DIM 6
#define XDIM 774      // IN+META
#define HID 256
#define OUT_D 128
#define NEXP 4
#define NET_T 3
#define REL_D 200
#define NLAY 4
#define FF_D 512

typedef __attribute__((ext_vector_type(8))) short short8;
typedef __attribute__((ext_vector_type(4))) float f32x4;

__device__ __forceinline__ ushort f2bf(float f) {
    union { float f; unsigned u; } a; a.f = f;
    unsigned u = a.u;
    unsigned r = (u + 0x7FFFu + ((u >> 16) & 1u)) >> 16;  // RNE
    return (ushort)r;
}
__device__ __forceinline__ float bf2f(ushort h) {
    union { unsigned u; float f; } a; a.u = ((unsigned)h) << 16;
    return a.f;
}
__device__ __forceinline__ unsigned packsplit(float v) {
    ushort h = f2bf(v);
    ushort lo = f2bf(v - bf2f(h));
    return ((unsigned)h << 16) | lo;
}

// ---------------------------------------------------------------------------
// fp32 -> packed (hi<<16|lo) split with K padding (weights only now).
// ---------------------------------------------------------------------------
__global__ void cvt_pack_kernel(const float* __restrict__ src, int ldsrc, int Kreal,
                                unsigned* __restrict__ pk, int R, int ldp)
{
    size_t i = (size_t)blockIdx.x * blockDim.x + threadIdx.x;
    size_t total = (size_t)R * ldp;
    if (i >= total) return;
    int col = (int)(i % ldp);
    int row = (int)(i / ldp);
    float v = (col < Kreal) ? src[(size_t)row * ldsrc + col] : 0.f;
    pk[i] = packsplit(v);
}

static void cvt_pack(const float* src, int ldsrc, int Kreal, unsigned* pk,
                     int R, int ldp, hipStream_t s)
{
    size_t total = (size_t)R * ldp;
    cvt_pack_kernel<<<(int)((total + 255) / 256), 256, 0, s>>>(src, ldsrc, Kreal, pk, R, ldp);
}

// ---------------------------------------------------------------------------
// Split-bf16 (3xMFMA) fp32-precision GEMM.
// Block tile (32*WM) x 64, 2x2 waves, wave tile (16*WM) x 32, K-step 32.
// A: packed uint (A_FP32=0) or fp32 with col<Kreal guard (A_FP32=1).
// B: fp32 (in-kernel split) or packed uint. Pipelined staging.
// ACT: 0=none,1=relu,2=elu. HAS_RES: +res. OUT_SPLIT: write packed pair.
// ---------------------------------------------------------------------------
template<int WM, int ACT, int HAS_RES, int OUT_SPLIT, int A_FP32, int B_PACKED>
__global__ __launch_bounds__(256) void mfma3k(
    const void* __restrict__ Ap, int lda, int Kreal,
    const void* __restrict__ Bp, int ldb,
    const float* __restrict__ bias, const float* __restrict__ res,
    float* __restrict__ C, unsigned* __restrict__ Cpk,
    int M, int Nn, int K)
{
    const int BM = 32 * WM;
    __shared__ __align__(16) ushort Ash[BM * 40];
    __shared__ __align__(16) ushort Asl[BM * 40];
    __shared__ __align__(16) ushort Bsh[64 * 40];
    __shared__ __align__(16) ushort Bsl[64 * 40];

    const unsigned* Ak = (const unsigned*)Ap;
    const float*    Af = (const float*)Ap;
    const unsigned* Bk = (const unsigned*)Bp;
    const float*    Bf = (const float*)Bp;

    int bn = blockIdx.x * 64;
    int bm = blockIdx.y * BM;
    int t = threadIdx.x;
    int wave = t >> 6, lane = t & 63;
    int wm = wave & 1, wn = wave >> 1;
    int quad = lane >> 4, r = lane & 15;

    const int ACH = (BM * 4) / 256;      // chunks (8 cols) per thread: 2 or 1

    uint4 apk[2][2];
    float afp[2][8];
    uint4 bpk[2];
    float4 bfp[2];

    auto loadA = [&](int k0) {
#pragma unroll
        for (int i = 0; i < ACH; i++) {
            int idx = t + i * 256;
            int row = idx >> 2, c8 = idx & 3;
            int grow = bm + row; if (grow > M - 1) grow = M - 1;
            if (A_FP32) {
                int cb = k0 + c8 * 8;
                const float* p = Af + (size_t)grow * lda + cb;
                if (cb + 8 <= Kreal) {
                    float2 f0 = *(const float2*)p,     f1 = *(const float2*)(p + 2);
                    float2 f2 = *(const float2*)(p + 4), f3 = *(const float2*)(p + 6);
                    afp[i][0] = f0.x; afp[i][1] = f0.y; afp[i][2] = f1.x; afp[i][3] = f1.y;
                    afp[i][4] = f2.x; afp[i][5] = f2.y; afp[i][6] = f3.x; afp[i][7] = f3.y;
                } else {
#pragma unroll
                    for (int e = 0; e < 8; e++)
                        afp[i][e] = (cb + e < Kreal) ? p[e] : 0.f;
                }
            } else {
                const unsigned* p = Ak + (size_t)grow * lda + k0 + c8 * 8;
                apk[i][0] = *(const uint4*)p; apk[i][1] = *(const uint4*)(p + 4);
            }
        }
    };
    auto loadB = [&](int k0) {
        int row = t >> 2, c8 = t & 3;
        if (B_PACKED) {
            const unsigned* p = Bk + (size_t)(bn + row) * ldb + k0 + c8 * 8;
            bpk[0] = *(const uint4*)p; bpk[1] = *(const uint4*)(p + 4);
        } else {
            const float* p = Bf + (size_t)(bn + row) * ldb + k0 + c8 * 8;
            bfp[0] = *(const float4*)p; bfp[1] = *(const float4*)(p + 4);
        }
    };
    auto storeTiles = [&]() {
#pragma unroll
        for (int i = 0; i < ACH; i++) {
            int idx = t + i * 256;
            int row = idx >> 2, c8 = idx & 3;
            short8 hi, lo;
            if (A_FP32) {
#pragma unroll
                for (int e = 0; e < 8; e++) {
                    ushort h = f2bf(afp[i][e]);
                    hi[e] = (short)h;
                    lo[e] = (short)f2bf(afp[i][e] - bf2f(h));
                }
            } else {
                unsigned u[8] = {apk[i][0].x, apk[i][0].y, apk[i][0].z, apk[i][0].w,
                                 apk[i][1].x, apk[i][1].y, apk[i][1].z, apk[i][1].w};
#pragma unroll
                for (int e = 0; e < 8; e++) { hi[e] = (short)(u[e] >> 16); lo[e] = (short)(u[e] & 0xFFFFu); }
            }
            *(short8*)&Ash[row * 40 + c8 * 8] = hi;
            *(short8*)&Asl[row * 40 + c8 * 8] = lo;
        }
        {
            int row = t >> 2, c8 = t & 3;
            short8 hi, lo;
            if (B_PACKED) {
                unsigned u[8] = {bpk[0].x, bpk[0].y, bpk[0].z, bpk[0].w,
                                 bpk[1].x, bpk[1].y, bpk[1].z, bpk[1].w};
#pragma unroll
                for (int e = 0; e < 8; e++) { hi[e] = (short)(u[e] >> 16); lo[e] = (short)(u[e] & 0xFFFFu); }
            } else {
                float f[8] = {bfp[0].x, bfp[0].y, bfp[0].z, bfp[0].w,
                              bfp[1].x, bfp[1].y, bfp[1].z, bfp[1].w};
#pragma unroll
                for (int e = 0; e < 8; e++) {
                    ushort h = f2bf(f[e]);
                    hi[e] = (short)h;
                    lo[e] = (short)f2bf(f[e] - bf2f(h));
                }
            }
            *(short8*)&Bsh[row * 40 + c8 * 8] = hi;
            *(short8*)&Bsl[row * 40 + c8 * 8] = lo;
        }
    };

    f32x4 acc[WM][2];
#pragma unroll
    for (int i = 0; i < WM; i++)
#pragma unroll
        for (int j = 0; j < 2; j++) acc[i][j] = (f32x4){0.f, 0.f, 0.f, 0.f};

    loadA(0); loadB(0);
    for (int k0 = 0; k0 < K; k0 += 32) {
        storeTiles();
        __syncthreads();
        if (k0 + 32 < K) { loadA(k0 + 32); loadB(k0 + 32); }

        short8 ah[WM], al[WM];
#pragma unroll
        for (int i = 0; i < WM; i++) {
            int ro = (wm * (WM * 16) + i * 16 + r) * 40 + quad * 8;
            ah[i] = *(const short8*)&Ash[ro];
            al[i] = *(const short8*)&Asl[ro];
        }
#pragma unroll
        for (int j = 0; j < 2; j++) {
            int ro = (wn * 32 + j * 16 + r) * 40 + quad * 8;
            short8 bh = *(const short8*)&Bsh[ro];
            short8 bl = *(const short8*)&Bsl[ro];
#pragma unroll
            for (int i = 0; i < WM; i++)
                acc[i][j] = __builtin_amdgcn_mfma_f32_16x16x32_bf16(ah[i], bh, acc[i][j], 0, 0, 0);
#pragma unroll
            for (int i = 0; i < WM; i++)
                acc[i][j] = __builtin_amdgcn_mfma_f32_16x16x32_bf16(ah[i], bl, acc[i][j], 0, 0, 0);
#pragma unroll
            for (int i = 0; i < WM; i++)
                acc[i][j] = __builtin_amdgcn_mfma_f32_16x16x32_bf16(al[i], bh, acc[i][j], 0, 0, 0);
        }
        __syncthreads();
    }

    // epilogue
#pragma unroll
    for (int j = 0; j < 2; j++) {
        int col = bn + wn * 32 + j * 16 + r;
        float bc = bias ? bias[col] : 0.f;
#pragma unroll
        for (int i = 0; i < WM; i++) {
#pragma unroll
            for (int reg = 0; reg < 4; reg++) {
                int row = bm + wm * (WM * 16) + i * 16 + quad * 4 + reg;
                if (row >= M) continue;
                float v = acc[i][j][reg] + bc;
                if (HAS_RES) v += res[(size_t)row * Nn + col];
                if (ACT == 1) v = fmaxf(v, 0.f);
                else if (ACT == 2) v = (v > 0.f) ? v : expm1f(v);
                if (OUT_SPLIT) Cpk[(size_t)row * Nn + col] = packsplit(v);
                else           C[(size_t)row * Nn + col] = v;
            }
        }
    }
}

template<int WM, int ACT, int HAS_RES, int OUT_SPLIT, int A_FP32, int B_PACKED>
static void m3_launch(const void* Ap, int lda, int Kreal, const void* Bp, int ldb,
                      const float* bias, const float* res,
                      float* C, unsigned* Cpk,
                      int M, int Nn, int K, hipStream_t s)
{
    const int BM = 32 * WM;
    dim3 grid(Nn / 64, (M + BM - 1) / BM);
    mfma3k<WM, ACT, HAS_RES, OUT_SPLIT, A_FP32, B_PACKED><<<grid, 256, 0, s>>>(
        Ap, lda, Kreal, Bp, ldb, bias, res, C, Cpk, M, Nn, K);
}

// ---------------------------------------------------------------------------
// fp32 tiled GEMM (tiny me_w1 only, K=6)
// ---------------------------------------------------------------------------
template<int ACT>
__global__ void gemm_kernel(const float* __restrict__ A, int lda,
                            const float* __restrict__ Bw,
                            const float* __restrict__ bias,
                            const float* __restrict__ res,
                            float* __restrict__ C, int M, int Nn, int K)
{
    __shared__ float As[16][68];
    __shared__ float Bs[16][68];
    int bm = blockIdx.y * 64, bn = blockIdx.x * 64;
    int t = threadIdx.x;
    int tx = t & 15, ty = t >> 4;
    float acc[4][4] = {{0.f}};

    for (int k0 = 0; k0 < K; k0 += 16) {
#pragma unroll
        for (int i = 0; i < 4; i++) {
            int l = t * 4 + i; int mm = l >> 4, kk = l & 15;
            int gm = bm + mm, gk = k0 + kk;
            As[kk][mm] = (gm < M && gk < K) ? A[(size_t)gm * lda + gk] : 0.f;
        }
#pragma unroll
        for (int i = 0; i < 4; i++) {
            int l = t * 4 + i; int nn = l >> 4, kk = l & 15;
            int gn = bn + nn, gk = k0 + kk;
            Bs[kk][nn] = (gn < Nn && gk < K) ? Bw[(size_t)gn * K + gk] : 0.f;
        }
        __syncthreads();
#pragma unroll
        for (int kk = 0; kk < 16; kk++) {
            float4 a4 = *reinterpret_cast<const float4*>(&As[kk][ty * 4]);
            float4 b4 = *reinterpret_cast<const float4*>(&Bs[kk][tx * 4]);
            float a0[4] = {a4.x, a4.y, a4.z, a4.w};
            float b0[4] = {b4.x, b4.y, b4.z, b4.w};
#pragma unroll
            for (int i = 0; i < 4; i++)
#pragma unroll
                for (int j = 0; j < 4; j++)
                    acc[i][j] += a0[i] * b0[j];
        }
        __syncthreads();
    }
#pragma unroll
    for (int i = 0; i < 4; i++) {
        int gm = bm + ty * 4 + i; if (gm >= M) continue;
#pragma unroll
        for (int j = 0; j < 4; j++) {
            int gn = bn + tx * 4 + j; if (gn >= Nn) continue;
            float v = acc[i][j];
            if (bias) v += bias[gn];
            if (res)  v += res[(size_t)gm * Nn + gn];
            if (ACT == 1) v = fmaxf(v, 0.f);
            C[(size_t)gm * Nn + gn] = v;
        }
    }
}

// ---------------------------------------------------------------------------
// bf16 MFMA GEMM (downstream-of-gate): 64x64 tile, 2x2 waves of 32x32,
// pipelined. A fp32 or bf16; B fp32. Batched over z (A shared if strideAz=0).
// ---------------------------------------------------------------------------
template<int ACT, int A_BF16, int OUT_BF16>
__global__ __launch_bounds__(256) void mfma_gemm(
    const void* __restrict__ Ap, size_t strideAz,
    const float* __restrict__ Bw, size_t strideBz,
    const float* __restrict__ bias, size_t strideBiasz,
    void* __restrict__ Cp, size_t strideCz,
    int M, int Nn, int K)
{
    __shared__ __align__(16) ushort As[64 * 40];
    __shared__ __align__(16) ushort Bs[64 * 40];

    int z = blockIdx.z;
    const float*  Af  = (const float*)Ap  + (A_BF16 ? 0 : z * strideAz);
    const ushort* Ab  = (const ushort*)Ap + (A_BF16 ? z * strideAz : 0);
    const float*  Bwz = Bw + z * strideBz;
    const float*  bz  = bias ? bias + z * strideBiasz : nullptr;
    float*  Cf = (float*)Cp  + (OUT_BF16 ? 0 : z * strideCz);
    ushort* Cb = (ushort*)Cp + (OUT_BF16 ? z * strideCz : 0);

    int bn = blockIdx.x * 64;
    int bm = blockIdx.y * 64;
    int t = threadIdx.x;
    int wave = t >> 6, lane = t & 63;
    int wm = wave & 1, wn = wave >> 1;
    int quad = lane >> 4, r = lane & 15;

    short8 apre_b;
    float4 apre_f[2];
    float4 bpre[2];
    int ar = t >> 2, ac = t & 3;

    auto loadA = [&](int k0) {
        if (A_BF16) {
            apre_b = *(const short8*)(Ab + (size_t)(bm + ar) * K + k0 + ac * 8);
        } else {
#pragma unroll
            for (int i = 0; i < 2; i++) {
                int idx = t + i * 256;
                int row = idx >> 3, c4 = idx & 7;
                apre_f[i] = *(const float4*)(Af + (size_t)(bm + row) * K + k0 + c4 * 4);
            }
        }
    };
    auto loadB = [&](int k0) {
        const float* p = Bwz + (size_t)(bn + ar) * K + k0 + ac * 8;
        bpre[0] = *(const float4*)p;
        bpre[1] = *(const float4*)(p + 4);
    };
    auto storeTiles = [&]() {
        if (A_BF16) {
            *(short8*)&As[ar * 40 + ac * 8] = apre_b;
        } else {
#pragma unroll
            for (int i = 0; i < 2; i++) {
                int idx = t + i * 256;
                int row = idx >> 3, c4 = idx & 7;
                ushort4 u;
                u.x = f2bf(apre_f[i].x); u.y = f2bf(apre_f[i].y);
                u.z = f2bf(apre_f[i].z); u.w = f2bf(apre_f[i].w);
                *(ushort4*)&As[row * 40 + c4 * 4] = u;
            }
        }
        {
            float f[8] = {bpre[0].x, bpre[0].y, bpre[0].z, bpre[0].w,
                          bpre[1].x, bpre[1].y, bpre[1].z, bpre[1].w};
            short8 hb;
#pragma unroll
            for (int e = 0; e < 8; e++) hb[e] = (short)f2bf(f[e]);
            *(short8*)&Bs[ar * 40 + ac * 8] = hb;
        }
    };

    f32x4 acc[2][2];
#pragma unroll
    for (int i = 0; i < 2; i++)
#pragma unroll
        for (int j = 0; j < 2; j++) acc[i][j] = (f32x4){0.f, 0.f, 0.f, 0.f};

    loadA(0); loadB(0);
    for (int k0 = 0; k0 < K; k0 += 32) {
        storeTiles();
        __syncthreads();
        if (k0 + 32 < K) { loadA(k0 + 32); loadB(k0 + 32); }

        short8 af[2];
#pragma unroll
        for (int i = 0; i < 2; i++)
            af[i] = *(const short8*)&As[(wm * 32 + i * 16 + r) * 40 + quad * 8];
#pragma unroll
        for (int j = 0; j < 2; j++) {
            short8 bf = *(const short8*)&Bs[(wn * 32 + j * 16 + r) * 40 + quad * 8];
#pragma unroll
            for (int i = 0; i < 2; i++)
                acc[i][j] = __builtin_amdgcn_mfma_f32_16x16x32_bf16(af[i], bf, acc[i][j], 0, 0, 0);
        }
        __syncthreads();
    }

#pragma unroll
    for (int j = 0; j < 2; j++) {
        int col = bn + wn * 32 + j * 16 + r;
        float bc = bz ? bz[col] : 0.f;
#pragma unroll
        for (int i = 0; i < 2; i++) {
#pragma unroll
            for (int reg = 0; reg < 4; reg++) {
                int row = bm + wm * 32 + i * 16 + quad * 4 + reg;
                float v = acc[i][j][reg] + bc;
                if (ACT == 1) v = fmaxf(v, 0.f);
                if (OUT_BF16) Cb[(size_t)row * Nn + col] = f2bf(v);
                else          Cf[(size_t)row * Nn + col] = v;
            }
        }
    }
}

template<int ACT, int A_BF16, int OUT_BF16>
static void mfma_launch(const void* A, size_t sAz, const float* Bw, size_t sBz,
                        const float* bias, size_t sbz, void* C, size_t sCz,
                        int M, int Nn, int K, int batch, hipStream_t s)
{
    dim3 grid(Nn / 64, M / 64, batch);
    mfma_gemm<ACT, A_BF16, OUT_BF16><<<grid, 256, 0, s>>>(A, sAz, Bw, sBz, bias, sbz, C, sCz, M, Nn, K);
}

// ---------------------------------------------------------------------------
// GNN helper kernels
// ---------------------------------------------------------------------------
__global__ void sisj_kernel(const float* __restrict__ Wx, const float* __restrict__ a,
                            float* __restrict__ s_i, float* __restrict__ s_j, int n)
{
    int t = threadIdx.x; int w = t >> 6, l = t & 63;
    int m = blockIdx.x * 4 + w; if (m >= n) return;
    const float* r = Wx + (size_t)m * HID;
    float v1 = 0.f, v2 = 0.f;
#pragma unroll
    for (int i = 0; i < 4; i++) {
        float xv = r[l + 64 * i];
        v1 += xv * a[l + 64 * i];
        v2 += xv * a[HID + l + 64 * i];
    }
    for (int off = 32; off; off >>= 1) { v1 += __shfl_down(v1, off); v2 += __shfl_down(v2, off); }
    if (l == 0) { s_i[m] = v1; s_j[m] = v2; }
}

__global__ void rs_kernel(const float* __restrict__ Wr, const float* __restrict__ rel,
                          const float* __restrict__ a3, float* __restrict__ rs)
{
    __shared__ float red[256];
    int tt = blockIdx.x; int j = threadIdx.x;
    const float* relr = rel + tt * REL_D;
    const float* wr = Wr + (size_t)j * REL_D;
    float wsum = 0.f;
    for (int k = 0; k < REL_D; k++) wsum += wr[k] * relr[k];
    red[j] = wsum * a3[j];
    __syncthreads();
    for (int s2 = 128; s2; s2 >>= 1) { if (j < s2) red[j] += red[j + s2]; __syncthreads(); }
    if (j == 0) rs[tt] = red[0];
}

// ---- CSR build ----
__global__ void deg_kernel(const int* __restrict__ dst, int* __restrict__ deg)
{
    int e = blockIdx.x * blockDim.x + threadIdx.x;
    if (e < EE) atomicAdd(&deg[dst[e]], 1);
}

__global__ void scan_kernel(const int* __restrict__ deg, int* __restrict__ rowstart,
                            int* __restrict__ cursor, int n)
{
    __shared__ int bs[1024];
    int t = threadIdx.x;
    int base = t * 40;
    int loc[40];
    int sum = 0;
#pragma unroll
    for (int i = 0; i < 40; i++) {
        int v = (base + i < n) ? deg[base + i] : 0;
        loc[i] = sum; sum += v;
    }
    bs[t] = sum;
    __syncthreads();
    for (int off = 1; off < 1024; off <<= 1) {
        int x = (t >= off) ? bs[t - off] : 0;
        __syncthreads();
        bs[t] += x;
        __syncthreads();
    }
    int excl = bs[t] - sum;
#pragma unroll
    for (int i = 0; i < 40; i++) {
        if (base + i < n) { int v = excl + loc[i]; rowstart[base + i] = v; cursor[base + i] = v; }
    }
    if (t == 1023) rowstart[n] = bs[1023];
}

__global__ void fill_kernel(const int* __restrict__ src, const int* __restrict__ dst,
                            const int* __restrict__ et, int* __restrict__ cursor,
                            unsigned* __restrict__ csr_val)
{
    int e = blockIdx.x * blockDim.x + threadIdx.x;
    if (e >= EE) return;
    int d = dst[e];
    int pos = atomicAdd(&cursor[d], 1);
    csr_val[pos] = (unsigned)src[e] | ((unsigned)et[e] << 16);
}

// ---- fused attention-softmax aggregation: wave per dst node (< nlim) ----
__global__ void csr_agg_kernel(const unsigned* __restrict__ csr_val,
                               const int* __restrict__ rowstart,
                               const float* __restrict__ s_i, const float* __restrict__ s_j,
                               const float* __restrict__ rsv,
                               const float* __restrict__ Wx, float* __restrict__ agg,
                               int nlim)
{
    int t = threadIdx.x; int w = t >> 6, l = t & 63;
    int node = blockIdx.x * 4 + w; if (node >= nlim) return;
    int start = rowstart[node], end = rowstart[node + 1];
    float r0 = rsv[0], r1 = rsv[1], r2 = rsv[2];
    float si = s_i[node];

    float m = -INFINITY;
    for (int i = start + l; i < end; i += 64) {
        unsigned v = csr_val[i];
        int s = v & 0xFFFF; int et = v >> 16;
        float rr = (et == 0) ? r0 : ((et == 1) ? r1 : r2);
        float lg = si + s_j[s] + rr;
        lg = (lg >= 0.f) ? lg : 0.2f * lg;
        m = fmaxf(m, lg);
    }
    for (int off = 32; off; off >>= 1) m = fmaxf(m, __shfl_down(m, off));
    m = __shfl(m, 0);

    float a0 = 0.f, a1 = 0.f, a2 = 0.f, a3 = 0.f, ssum = 0.f;
    for (int c = start; c < end; c += 64) {
        int nchunk = min(64, end - c);
        float wgt = 0.f; int sidx = 0;
        if (l < nchunk) {
            unsigned v = csr_val[c + l];
            sidx = v & 0xFFFF; int et = v >> 16;
            float rr = (et == 0) ? r0 : ((et == 1) ? r1 : r2);
            float lg = si + s_j[sidx] + rr;
            lg = (lg >= 0.f) ? lg : 0.2f * lg;
            wgt = expf(lg - m);
            ssum += wgt;
        }
        int j = 0;
        for (; j + 4 <= nchunk; j += 4) {
            float w0 = __shfl(wgt, j),     w1 = __shfl(wgt, j + 1);
            float w2 = __shfl(wgt, j + 2), w3 = __shfl(wgt, j + 3);
            int s0 = __shfl(sidx, j),     s1 = __shfl(sidx, j + 1);
            int s2 = __shfl(sidx, j + 2), s3 = __shfl(sidx, j + 3);
            const float* p0 = Wx + (size_t)s0 * HID + l;
            const float* p1 = Wx + (size_t)s1 * HID + l;
            const float* p2 = Wx + (size_t)s2 * HID + l;
            const float* p3 = Wx + (size_t)s3 * HID + l;
            float v00 = p0[0], v01 = p0[64], v02 = p0[128], v03 = p0[192];
            float v10 = p1[0], v11 = p1[64], v12 = p1[128], v13 = p1[192];
            float v20 = p2[0], v21 = p2[64], v22 = p2[128], v23 = p2[192];
            float v30 = p3[0], v31 = p3[64], v32 = p3[128], v33 = p3[192];
            a0 += w0 * v00 + w1 * v10 + w2 * v20 + w3 * v30;
            a1 += w0 * v01 + w1 * v11 + w2 * v21 + w3 * v31;
            a2 += w0 * v02 + w1 * v12 + w2 * v22 + w3 * v32;
            a3 += w0 * v03 + w1 * v13 + w2 * v23 + w3 * v33;
        }
        for (; j < nchunk; j++) {
            float wj = __shfl(wgt, j);
            int sj = __shfl(sidx, j);
            const float* wr = Wx + (size_t)sj * HID + l;
            a0 += wj * wr[0];
            a1 += wj * wr[64];
            a2 += wj * wr[128];
            a3 += wj * wr[192];
        }
    }
    for (int off = 32; off; off >>= 1) ssum += __shfl_down(ssum, off);
    ssum = __shfl(ssum, 0);
    float inv = 1.f / (ssum + 1e-16f);
    float* ar = agg + (size_t)node * HID;
    ar[l] = a0 * inv; ar[l + 64] = a1 * inv; ar[l + 128] = a2 * inv; ar[l + 192] = a3 * inv;
}

// row-L2-normalize a packed pair in place
__global__ void rownorm_pack(unsigned* __restrict__ pk, int n)
{
    int t = threadIdx.x; int w = t >> 6, l = t & 63;
    int m = blockIdx.x * 4 + w; if (m >= n) return;
    size_t base = (size_t)m * HID;
    float vals[4]; float q = 0.f;
#pragma unroll
    for (int i = 0; i < 4; i++) {
        unsigned u = pk[base + l + 64 * i];
        vals[i] = bf2f((ushort)(u >> 16)) + bf2f((ushort)(u & 0xFFFFu));
        q += vals[i] * vals[i];
    }
    for (int off = 32; off; off >>= 1) q += __shfl_down(q, off);
    q = __shfl(q, 0);
    float inv = 1.f / fmaxf(sqrtf(q), 1e-12f);
#pragma unroll
    for (int i = 0; i < 4; i++)
        pk[base + l + 64 * i] = packsplit(vals[i] * inv);
}

// ---------------------------------------------------------------------------
// MoE gating (fp32)
// ---------------------------------------------------------------------------
__global__ void moe_gate_kernel(const float* __restrict__ xv, const float* __restrict__ gate_w,
                                const float* __restrict__ noise_w, const float* __restrict__ eps,
                                float* __restrict__ comb, float* __restrict__ tmpsum)
{
    __shared__ float part[4];
    int t = threadIdx.x; int w = t >> 6, l = t & 63;
    if (t < 4) part[t] = 0.f;
    __syncthreads();
    int b = blockIdx.x * 4 + w;
    const float* xr = xv + (size_t)b * OUT_D;
    float x0 = xr[l], x1 = xr[l + 64];
    float dots[5];
#pragma unroll
    for (int e = 0; e < 4; e++) {
        const float* gw = gate_w + e * OUT_D;
        float v = x0 * gw[l] + x1 * gw[l + 64];
        for (int off = 32; off; off >>= 1) v += __shfl_down(v, off);
        dots[e] = v;
    }
    {
        float v = x0 * noise_w[l] + x1 * noise_w[l + 64];
        for (int off = 32; off; off >>= 1) v += __shfl_down(v, off);
        dots[4] = v;
    }
    if (l == 0) {
        float xg = dots[4];
        float nsd = (xg > 20.f) ? xg : log1pf(expf(xg));
        float hv[4];
#pragma unroll
        for (int e = 0; e < 4; e++) hv[e] = dots[e] + eps[(size_t)b * 4 + e] * nsd;
        int i1 = 0;
        for (int e = 1; e < 4; e++) if (hv[e] < hv[i1]) i1 = e;
        int i2 = -1;
        for (int e = 0; e < 4; e++) { if (e == i1) continue; if (i2 < 0 || hv[e] < hv[i2]) i2 = e; }
        int k1 = -1, k2 = -1;
        for (int e = 0; e < 4; e++) { if (e != i1 && e != i2) { if (k1 < 0) k1 = e; else k2 = e; } }
        float mm = fmaxf(hv[k1], hv[k2]);
        float e1 = expf(hv[k1] - mm), e2 = expf(hv[k2] - mm);
        float s = e1 + e2;
        float L[4] = {0.f, 0.f, 0.f, 0.f};
        L[k1] = e1 / s; L[k2] = e2 / s;
#pragma unroll
        for (int e = 0; e < 4; e++) comb[(size_t)b * 4 + e] = L[e];
        atomicAdd(&part[k1], L[k1]);
        atomicAdd(&part[k2], L[k2]);
    }
    __syncthreads();
    if (t < 4) atomicAdd(&tmpsum[t], part[t]);
}

__global__ void moe_combine_kernel(const float* __restrict__ eo, const float* __restrict__ comb,
                                   float* __restrict__ zout)
{
    int idx = blockIdx.x * blockDim.x + threadIdx.x;
    if (idx >= BB * OUT_D) return;
    int b = idx >> 7, o = idx & 127;
    const size_t S = (size_t)BB * OUT_D;
    float v = comb[b * 4 + 0] * eo[idx] + comb[b * 4 + 1] * eo[idx + S]
            + comb[b * 4 + 2] * eo[idx + 2 * S] + comb[b * 4 + 3] * eo[idx + 3 * S];
    zout[(size_t)b * (3 * OUT_D) + o] = v;
}

__global__ void loss_kernel(const float* __restrict__ tmpsum, float* __restrict__ out)
{
    if (threadIdx.x == 0 && blockIdx.x == 0) {
        float total = 0.f;
        for (int v = 0; v < 3; v++) {
            const float* tp = tmpsum + v * 4;
            float mean = (tp[0] + tp[1] + tp[2] + tp[3]) * 0.25f;
            float var = 0.f;
            for (int e = 0; e < 4; e++) { float d = tp[e] - mean; var += d * d; }
            var /= 3.f;
            float r = sqrtf(var) / mean;
            total += r * r;
        }
        out[0] = total;
    }
}

// ---------------------------------------------------------------------------
// Transformer small kernels
// ---------------------------------------------------------------------------
__global__ void attn_kernel(const float* __restrict__ qkv, float* __restrict__ o)
{
    int t = threadIdx.x;
    int half = t >> 5;
    int d = t & 31;
    int task = blockIdx.x * 8 + half;   // b*4 + h
    int b = task >> 2, h = task & 3;
    const float* base = qkv + (size_t)b * 3 * 384 + h * 32;
    float q0 = base[d],       q1 = base[384 + d],       q2 = base[768 + d];
    float k0 = base[128 + d], k1 = base[384 + 128 + d], k2 = base[768 + 128 + d];
    float v0 = base[256 + d], v1 = base[384 + 256 + d], v2 = base[768 + 256 + d];
    float s[3][3];
    s[0][0] = q0 * k0; s[0][1] = q0 * k1; s[0][2] = q0 * k2;
    s[1][0] = q1 * k0; s[1][1] = q1 * k1; s[1][2] = q1 * k2;
    s[2][0] = q2 * k0; s[2][1] = q2 * k1; s[2][2] = q2 * k2;
#pragma unroll
    for (int i = 0; i < 3; i++)
#pragma unroll
        for (int j = 0; j < 3; j++) {
            float v = s[i][j];
            for (int off = 16; off; off >>= 1) v += __shfl_xor(v, off, 32);
            s[i][j] = v;
        }
    const float scale = 0.17677669529663687f;
    float outv[3];
#pragma unroll
    for (int i = 0; i < 3; i++) {
        float a0 = s[i][0] * scale, a1 = s[i][1] * scale, a2 = s[i][2] * scale;
        float m = fmaxf(a0, fmaxf(a1, a2));
        float e0 = expf(a0 - m), e1 = expf(a1 - m), e2 = expf(a2 - m);
        float inv = 1.f / (e0 + e1 + e2);
        outv[i] = (e0 * v0 + e1 * v1 + e2 * v2) * inv;
    }
    float* ob = o + (size_t)b * 3 * 128 + h * 32;
    ob[d] = outv[0]; ob[128 + d] = outv[1]; ob[256 + d] = outv[2];
}

__global__ void ln_residual_kernel(float* __restrict__ x, const float* __restrict__ add,
                                   const float* __restrict__ g, const float* __restrict__ bta, int M)
{
    int t = threadIdx.x; int w = t >> 6, l = t & 63;
    int row = blockIdx.x * 4 + w; if (row >= M) return;
    float* xr = x + (size_t)row * 128;
    const float* ar = add + (size_t)row * 128;
    float v0 = xr[l] + ar[l], v1 = xr[l + 64] + ar[l + 64];
    float s = v0 + v1;
    for (int off = 32; off; off >>= 1) s += __shfl_down(s, off);
    s = __shfl(s, 0);
    float mu = s * (1.f / 128.f);
    float d0 = v0 - mu, d1 = v1 - mu;
    float q = d0 * d0 + d1 * d1;
    for (int off = 32; off; off >>= 1) q += __shfl_down(q, off);
    q = __shfl(q, 0);
    float inv = rsqrtf(q * (1.f / 128.f) + 1e-5f);
    xr[l]      = d0 * inv * g[l] + bta[l];
    xr[l + 64] = d1 * inv * g[l + 64] + bta[l + 64];
}

__global__ void clf_kernel(const float* __restrict__ z, const float* __restrict__ w,
                           const float* __restrict__ b, float* __restrict__ out)
{
    int t = threadIdx.x; int wv = t >> 6, l = t & 63;
    int row = blockIdx.x * 4 + wv; if (row >= BB) return;
    const float* zr = z + (size_t)row * 384;
    float v0 = 0.f, v1 = 0.f;
    for (int i = l; i < 384; i += 64) {
        float zz = zr[i];
        v0 += zz * w[i];
        v1 += zz * w[384 + i];
    }
    for (int off = 32; off; off >>= 1) { v0 += __shfl_down(v0, off); v1 += __shfl_down(v1, off); }
    if (l == 0) { out[row * 2] = v0 + b[0]; out[row * 2 + 1] = v1 + b[1]; }
}

// ---------------------------------------------------------------------------
// Orchestration
// ---------------------------------------------------------------------------
extern "C" void kernel_launch(void* const* d_in, const int* in_sizes, int n_in,
                              void* d_out, int out_size, void* d_ws, size_t ws_size,
                              hipStream_t stream)
{
    const float* x         = (const float*)d_in[0];
    const float* noise     = (const float*)d_in[1];
    const float* g_lin1_w  = (const float*)d_in[2];
    const float* g_lin1_b  = (const float*)d_in[3];
    const float* conv_W    = (const float*)d_in[4];
    const float* conv_Wr   = (const float*)d_in[5];
    const float* conv_a    = (const float*)d_in[6];
    const float* conv_Wres = (const float*)d_in[7];
    const float* conv_rel  = (const float*)d_in[8];
    const float* g_lin2_w  = (const float*)d_in[9];
    const float* g_lin2_b  = (const float*)d_in[10];
    const float* te_w      = (const float*)d_in[11];
    const float* te_b      = (const float*)d_in[12];
    const float* me_w1     = (const float*)d_in[13];
    const float* me_b1     = (const float*)d_in[14];
    const float* me_w2     = (const float*)d_in[15];
    const float* me_b2     = (const float*)d_in[16];
    const float* moe_gate_w  = (const float*)d_in[17];
    const float* moe_noise_w = (const float*)d_in[18];
    const float* moe_w1    = (const float*)d_in[19];
    const float* moe_b1    = (const float*)d_in[20];
    const float* moe_w2    = (const float*)d_in[21];
    const float* moe_b2    = (const float*)d_in[22];
    const float* tf_qkv_w  = (const float*)d_in[23];
    const float* tf_qkv_b  = (const float*)d_in[24];
    const float* tf_out_w  = (const float*)d_in[25];
    const float* tf_out_b  = (const float*)d_in[26];
    const float* tf_ln1_g  = (const float*)d_in[27];
    const float* tf_ln1_b  = (const float*)d_in[28];
    const float* tf_ff1_w  = (const float*)d_in[29];
    const float* tf_ff1_b  = (const float*)d_in[30];
    const float* tf_ff2_w  = (const float*)d_in[31];
    const float* tf_ff2_b  = (const float*)d_in[32];
    const float* tf_ln2_g  = (const float*)d_in[33];
    const float* tf_ln2_b  = (const float*)d_in[34];
    const float* clf_w     = (const float*)d_in[35];
    const float* clf_b     = (const float*)d_in[36];
    const int*   edge_index = (const int*)d_in[37];
    const int*   edge_type  = (const int*)d_in[38];

    float* ws = (float*)d_ws;

    // Arena (float offsets)
    const size_t F_A = 0;          // hApk (40000x256 uint) / qkv
    const size_t F_B = 10240000;   // wx / graph / ff1bf
    const size_t F_C = 22822912;   // agg / x_mh / h1bf / attn_o+tmp1
    const size_t F_D = 33062912;   // hBpk / z,x_t,x_m,eo
    const size_t F_M = 43302912;   // misc + CSR
    const size_t F_X = 44200000;   // wpk

    unsigned* hApk = (unsigned*)(ws + F_A);
    float* qkv    = ws + F_A;
    float* wx     = ws + F_B;
    float* graph  = ws + F_B;
    ushort* ff1bf = (ushort*)(ws + F_B);
    float* agg    = ws + F_C;
    float* x_mh   = ws + F_C;
    ushort* h1bf  = (ushort*)(ws + F_C);
    float* attn_o = ws + F_C;
    float* tmp1   = ws + F_C + 3200000;
    unsigned* hBpk = (unsigned*)(ws + F_D);
    float* z      = ws + F_D;
    float* x_t    = ws + F_D + 3200000;
    float* x_m    = ws + F_D + 4300000;
    float* eo     = ws + F_D + 5400000;

    float* s_i    = ws + F_M;
    float* s_j    = ws + F_M + 40000;
    float* rsv    = ws + F_M + 80000;
    float* comb   = ws + F_M + 80016;
    float* tmpsum = ws + F_M + 112784;
    int* deg      = (int*)(ws + F_M + 120000);
    int* rowstart = (int*)(ws + F_M + 161000);
    int* cursor   = (int*)(ws + F_M + 202000);
    unsigned* csr_val = (unsigned*)(ws + F_M + 242000);

    unsigned* wpk  = (unsigned*)(ws + F_X);   // 256x800

    const int* srcv = edge_index;
    const int* dstv = edge_index + EE;

    // ---- 0. CSR build ----
    hipMemsetAsync(deg, 0, NN * sizeof(int), stream);
    deg_kernel<<<(EE + 255) / 256, 256, 0, stream>>>(dstv, deg);
    scan_kernel<<<1, 1024, 0, stream>>>(deg, rowstart, cursor, NN);
    fill_kernel<<<(EE + 255) / 256, 256, 0, stream>>>(srcv, dstv, edge_type, cursor, csr_val);

    // ---- 1. h = relu(x @ g_lin1_w.T + b) -> packed pair A ----
    cvt_pack(g_lin1_w, XDIM, XDIM, wpk, HID, 800, stream);
    m3_launch<4, 1, 0, 1, 1, 1>(x, XDIM, XDIM, wpk, 800, g_lin1_b, nullptr,
                                nullptr, hApk, NN, HID, 800, stream);

    // ---- 2. two HGN layers (packed ping-pong A->B->A) ----
    unsigned *inpk = hApk, *outpk = hBpk;
    for (int layer = 0; layer < 2; layer++) {
        const float* W    = conv_W    + (size_t)layer * HID * HID;
        const float* Wr   = conv_Wr   + (size_t)layer * HID * REL_D;
        const float* a    = conv_a    + (size_t)layer * 3 * HID;
        const float* Wres = conv_Wres + (size_t)layer * HID * HID;
        const float* rel  = conv_rel  + (size_t)layer * NET_T * REL_D;
        int mOut = (layer == 1) ? BB : NN;   // final GNN output only needed for rows < BB

        m3_launch<4, 0, 0, 0, 0, 0>(inpk, HID, HID, W, HID, nullptr, nullptr,
                                    wx, nullptr, NN, HID, HID, stream);
        sisj_kernel<<<NN / 4, 256, 0, stream>>>(wx, a, s_i, s_j, NN);
        rs_kernel<<<NET_T, 256, 0, stream>>>(Wr, rel, a + 2 * HID, rsv);
        csr_agg_kernel<<<(mOut + 3) / 4, 256, 0, stream>>>(csr_val, rowstart, s_i, s_j, rsv, wx, agg, mOut);
        if (layer == 0)
            m3_launch<4, 2, 1, 1, 0, 0>(inpk, HID, HID, Wres, HID, nullptr, agg,
                                        nullptr, outpk, mOut, HID, HID, stream);
        else
            m3_launch<2, 2, 1, 1, 0, 0>(inpk, HID, HID, Wres, HID, nullptr, agg,
                                        nullptr, outpk, mOut, HID, HID, stream);
        unsigned* tp = inpk; inpk = outpk; outpk = tp;
    }
    rownorm_pack<<<BB / 4, 256, 0, stream>>>(inpk, BB);

    // ---- 3. graph = relu(h2 @ g_lin2.T + b), only first BB rows ----
    m3_launch<2, 1, 0, 0, 0, 0>(inpk, HID, HID, g_lin2_w, HID, g_lin2_b, nullptr,
                                graph, nullptr, BB, OUT_D, HID, stream);

    // ---- 4. view encoders ----
    m3_launch<2, 1, 0, 0, 1, 0>(x, XDIM, IN_DIM, te_w, IN_DIM, te_b, nullptr,
                                x_t, nullptr, BB, OUT_D, IN_DIM, stream);
    {
        dim3 g((HID + 63) / 64, (BB + 63) / 64);
        gemm_kernel<1><<<g, 256, 0, stream>>>(x + IN_DIM, XDIM, me_w1, me_b1, nullptr,
                                              x_mh, BB, HID, META_DIM);
    }
    m3_launch<2, 1, 0, 0, 1, 0>(x_mh, HID, HID, me_w2, HID, me_b2, nullptr,
                                x_m, nullptr, BB, OUT_D, HID, stream);

    // ---- 5. MoE per view: fp32 gate, bf16 MFMA experts ----
    hipMemsetAsync(tmpsum, 0, 16 * sizeof(float), stream);
    const float* xvs[3] = { graph, x_t, x_m };
    for (int v = 0; v < 3; v++) {
        const float* xv = xvs[v];
        moe_gate_kernel<<<BB / 4, 256, 0, stream>>>(
            xv, moe_gate_w + (size_t)v * NEXP * OUT_D, moe_noise_w + (size_t)v * OUT_D,
            noise + (size_t)v * BB * NEXP, comb, tmpsum + v * 4);
        mfma_launch<1, 0, 1>(xv, 0,
                             moe_w1 + (size_t)v * 4 * FF_D * OUT_D, (size_t)FF_D * OUT_D,
                             moe_b1 + (size_t)v * 4 * FF_D, FF_D,
                             h1bf, (size_t)BB * FF_D,
                             BB, FF_D, OUT_D, 4, stream);
        mfma_launch<0, 1, 0>(h1bf, (size_t)BB * FF_D,
                             moe_w2 + (size_t)v * 4 * OUT_D * FF_D, (size_t)OUT_D * FF_D,
                             moe_b2 + (size_t)v * 4 * OUT_D, OUT_D,
                             eo, (size_t)BB * OUT_D,
                             BB, OUT_D, FF_D, 4, stream);
        moe_combine_kernel<<<(BB * OUT_D) / 256, 256, 0, stream>>>(eo, comb, z + v * OUT_D);
    }

    // ---- 6. transformer x4 on z (24576,128) ----
    const int MT = BB * 3;
    for (int li = 0; li < NLAY; li++) {
        mfma_launch<0, 0, 0>(z, 0, tf_qkv_w + (size_t)li * 384 * 128, 0,
                             tf_qkv_b + li * 384, 0, qkv, 0, MT, 384, 128, 1, stream);
        attn_kernel<<<(BB * 4) / 8, 256, 0, stream>>>(qkv, attn_o);
        mfma_launch<0, 0, 0>(attn_o, 0, tf_out_w + (size_t)li * 128 * 128, 0,
                             tf_out_b + li * 128, 0, tmp1, 0, MT, 128, 128, 1, stream);
        ln_residual_kernel<<<MT / 4, 256, 0, stream>>>(z, tmp1, tf_ln1_g + li * 128, tf_ln1_b + li * 128, MT);
        mfma_launch<1, 0, 1>(z, 0, tf_ff1_w + (size_t)li * 512 * 128, 0,
                             tf_ff1_b + li * 512, 0, ff1bf, 0, MT, 512, 128, 1, stream);
        mfma_launch<0, 1, 0>(ff1bf, 0, tf_ff2_w + (size_t)li * 128 * 512, 0,
                             tf_ff2_b + li * 128, 0, tmp1, 0, MT, 128, 512, 1, stream);
        ln_residual_kernel<<<MT / 4, 256, 0, stream>>>(z, tmp1, tf_ln2_g + li * 128, tf_ln2_b + li * 128, MT);
    }

    // ---- 7. classifier + loss ----
    clf_kernel<<<BB / 4, 256, 0, stream>>>(z, clf_w, clf_b, (float*)d_out);
    loss_kernel<<<1, 64, 0, stream>>>(tmpsum, (float*)d_out + BB * 2);
}